// Round 2
// baseline (1935.438 us; speedup 1.0000x reference)
//
#include <hip/hip_runtime.h>
#include <cstdint>

#define H 128
#define TILE_M 64

__device__ __forceinline__ void ld4(float* d, const float* s) {
  float4 v = *(const float4*)s; d[0] = v.x; d[1] = v.y; d[2] = v.z; d[3] = v.w;
}
__device__ __forceinline__ void st4(float* d, const float* s) {
  float4 v; v.x = s[0]; v.y = s[1]; v.z = s[2]; v.w = s[3]; *(float4*)d = v;
}

// ---------------- CSR build ----------------
__global__ __launch_bounds__(256)
void zero_int(int* __restrict__ p, int n) {
  int i = blockIdx.x * blockDim.x + threadIdx.x;
  if (i < n) p[i] = 0;
}

__global__ __launch_bounds__(256)
void edge_hist(const int* __restrict__ dst, int* __restrict__ deg, int e) {
  int i = blockIdx.x * blockDim.x + threadIdx.x;
  if (i < e) atomicAdd(&deg[dst[i]], 1);
}

__global__ __launch_bounds__(1024)
void scan_block(const int* __restrict__ in, int* __restrict__ out,
                int* __restrict__ partials, int n) {
  __shared__ int sh[1024];
  int i = blockIdx.x * 1024 + threadIdx.x;
  int v = (i < n) ? in[i] : 0;
  sh[threadIdx.x] = v;
  __syncthreads();
  for (int off = 1; off < 1024; off <<= 1) {
    int t = (threadIdx.x >= (unsigned)off) ? sh[threadIdx.x - off] : 0;
    __syncthreads();
    sh[threadIdx.x] += t;
    __syncthreads();
  }
  if (i < n) out[i] = sh[threadIdx.x] - v;   // exclusive
  if (partials != nullptr && threadIdx.x == 1023) partials[blockIdx.x] = sh[1023];
}

__global__ __launch_bounds__(1024)
void scan_add(int* __restrict__ rp, const int* __restrict__ offs, int n, int total) {
  int i = blockIdx.x * 1024 + threadIdx.x;
  if (i < n) rp[i] += offs[blockIdx.x];
  if (i == 0) rp[n] = total;
}

__global__ __launch_bounds__(256)
void copy_int(const int* __restrict__ a, int* __restrict__ b, int n) {
  int i = blockIdx.x * blockDim.x + threadIdx.x;
  if (i < n) b[i] = a[i];
}

__global__ __launch_bounds__(256)
void edge_fill(const int* __restrict__ src, const int* __restrict__ dst,
               int* __restrict__ cur, int* __restrict__ col, int e) {
  int i = blockIdx.x * blockDim.x + threadIdx.x;
  if (i < e) {
    int p = atomicAdd(&cur[dst[i]], 1);
    col[p] = src[i];
  }
}

// ---------------- CSR mean aggregation: one wave per dst row ----------------
__global__ __launch_bounds__(256)
void sage_agg(const float* __restrict__ h, const int* __restrict__ rp,
              const int* __restrict__ col, float* __restrict__ out, int n) {
  int row = blockIdx.x * 4 + (threadIdx.x >> 6);
  if (row >= n) return;
  int lane = threadIdx.x & 63;
  int beg = rp[row], end = rp[row + 1];
  float sx = 0.f, sy = 0.f;
  int j = beg;
  for (; j + 2 <= end; j += 2) {
    int s0 = col[j], s1 = col[j + 1];
    float2 v0 = *(const float2*)(h + (size_t)s0 * H + lane * 2);
    float2 v1 = *(const float2*)(h + (size_t)s1 * H + lane * 2);
    sx += v0.x + v1.x; sy += v0.y + v1.y;
  }
  if (j < end) {
    int s0 = col[j];
    float2 v0 = *(const float2*)(h + (size_t)s0 * H + lane * 2);
    sx += v0.x; sy += v0.y;
  }
  int c = end - beg;
  float inv = 1.0f / (float)(c > 1 ? c : 1);
  float2 r; r.x = sx * inv; r.y = sy * inv;
  *(float2*)(out + (size_t)row * H + lane * 2) = r;
}

// ---------------- fused GEMM ----------------
// mode 0 (encoder): out = relu(A1 @ W1 + bias)
// mode 1 (update):  m = rownorm(A1@W1 + A2@W2 + bias); out = relu(bn(m + resid))
// NOTE: out may alias A1 (each block reads A1 only in its own 64-row range and
// all A1 reads are barrier-separated from the epilogue stores) — so A1/A2/resid/out
// deliberately carry NO __restrict__.
__global__ __launch_bounds__(256)
void gemm_fused(const float* A1, const float* __restrict__ W1,
                const float* A2, const float* __restrict__ W2,
                const float* __restrict__ bias, const float* resid,
                const float* __restrict__ bng, const float* __restrict__ bnb,
                const float* __restrict__ bnm, const float* __restrict__ bnv,
                float* out, int n, int mode) {
  __shared__ float Ws[64 * 128];   // 32 KB: 64 k-rows of W
  __shared__ float As[64 * 68];    // 17.4 KB: 64 rows x 64 k, stride 68 (16B aligned)
  const int tid = threadIdx.x;
  const int tm = tid >> 4;
  const int tn = tid & 15;
  const int row0 = blockIdx.x * TILE_M;

  float acc[4][8];
  #pragma unroll
  for (int j = 0; j < 4; ++j)
    #pragma unroll
    for (int i = 0; i < 8; ++i) acc[j][i] = 0.f;

  const int npass = (mode == 0) ? 2 : 4;
  for (int p = 0; p < npass; ++p) {
    const float* A = (p < 2) ? A1 : A2;
    const float* W = (p < 2) ? W1 : W2;
    const int k0 = (p & 1) << 6;
    {
      const float4* s = (const float4*)(W + k0 * H);
      float4* d = (float4*)Ws;
      #pragma unroll
      for (int i = 0; i < 8; ++i) d[i * 256 + tid] = s[i * 256 + tid];
    }
    {
      const int lr = tid >> 4;
      const int lk = (tid & 15) << 2;
      #pragma unroll
      for (int j = 0; j < 4; ++j) {
        int r = lr + (j << 4);
        int rg = row0 + r; rg = rg < n ? rg : n - 1;
        float4 v = *(const float4*)(A + (size_t)rg * H + k0 + lk);
        *(float4*)(&As[r * 68 + lk]) = v;
      }
    }
    __syncthreads();
    #pragma unroll 8
    for (int kk = 0; kk < 64; ++kk) {
      float4 w0 = *(const float4*)(&Ws[kk * H + (tn << 2)]);
      float4 w1 = *(const float4*)(&Ws[kk * H + 64 + (tn << 2)]);
      #pragma unroll
      for (int j = 0; j < 4; ++j) {
        float a = As[(tm + (j << 4)) * 68 + kk];
        acc[j][0] = fmaf(a, w0.x, acc[j][0]);
        acc[j][1] = fmaf(a, w0.y, acc[j][1]);
        acc[j][2] = fmaf(a, w0.z, acc[j][2]);
        acc[j][3] = fmaf(a, w0.w, acc[j][3]);
        acc[j][4] = fmaf(a, w1.x, acc[j][4]);
        acc[j][5] = fmaf(a, w1.y, acc[j][5]);
        acc[j][6] = fmaf(a, w1.z, acc[j][6]);
        acc[j][7] = fmaf(a, w1.w, acc[j][7]);
      }
    }
    __syncthreads();
  }

  const int c0 = tn << 2;
  const int c1 = 64 + c0;
  float bia[8];
  ld4(bia, bias + c0); ld4(bia + 4, bias + c1);

  if (mode == 0) {
    #pragma unroll
    for (int j = 0; j < 4; ++j) {
      int rg = row0 + tm + (j << 4);
      if (rg < n) {
        float o[8];
        #pragma unroll
        for (int i = 0; i < 8; ++i) o[i] = fmaxf(acc[j][i] + bia[i], 0.f);
        st4(out + (size_t)rg * H + c0, o);
        st4(out + (size_t)rg * H + c1, o + 4);
      }
    }
  } else {
    float sg[8], ofs[8];
    {
      float g[8], be[8], mm[8], vv[8];
      ld4(g, bng + c0);  ld4(g + 4, bng + c1);
      ld4(be, bnb + c0); ld4(be + 4, bnb + c1);
      ld4(mm, bnm + c0); ld4(mm + 4, bnm + c1);
      ld4(vv, bnv + c0); ld4(vv + 4, bnv + c1);
      #pragma unroll
      for (int i = 0; i < 8; ++i) {
        float s = rsqrtf(vv[i] + 1e-5f) * g[i];
        sg[i] = s;
        ofs[i] = be[i] - mm[i] * s;
      }
    }
    #pragma unroll
    for (int j = 0; j < 4; ++j) {
      float o[8];
      #pragma unroll
      for (int i = 0; i < 8; ++i) o[i] = acc[j][i] + bia[i];
      float ss = 0.f;
      #pragma unroll
      for (int i = 0; i < 8; ++i) ss = fmaf(o[i], o[i], ss);
      // row is owned by the 16 lanes sharing tm (lane bits 0..3 = tn)
      ss += __shfl_xor(ss, 1);
      ss += __shfl_xor(ss, 2);
      ss += __shfl_xor(ss, 4);
      ss += __shfl_xor(ss, 8);
      float inv = 1.0f / fmaxf(sqrtf(ss), 1e-12f);
      int rg = row0 + tm + (j << 4);
      if (rg < n) {
        float rr[8];
        ld4(rr, resid + (size_t)rg * H + c0);
        ld4(rr + 4, resid + (size_t)rg * H + c1);
        float y[8];
        #pragma unroll
        for (int i = 0; i < 8; ++i) {
          float t = fmaf(o[i], inv, rr[i]);
          y[i] = fmaxf(fmaf(t, sg[i], ofs[i]), 0.f);
        }
        st4(out + (size_t)rg * H + c0, y);
        st4(out + (size_t)rg * H + c1, y + 4);
      }
    }
  }
}

// ---------------- fused classifier: out = relu(h@W1+b1)@W2 + b2 ----------------
__global__ __launch_bounds__(256)
void classifier(const float* __restrict__ h, const float* __restrict__ W1,
                const float* __restrict__ b1, const float* __restrict__ W2,
                const float* __restrict__ b2, float* __restrict__ out, int n) {
  __shared__ float W1s[128 * 64];  // 32 KB
  __shared__ float W2s[64 * 32];   // 8 KB
  __shared__ float Hs[64 * 68];    // A tile, then hid tile
  const int tid = threadIdx.x;
  const int row0 = blockIdx.x * 64;
  {
    const float4* s = (const float4*)W1;
    float4* d = (float4*)W1s;
    #pragma unroll
    for (int i = 0; i < 8; ++i) d[i * 256 + tid] = s[i * 256 + tid];
    const float4* s2 = (const float4*)W2;
    float4* d2 = (float4*)W2s;
    #pragma unroll
    for (int i = 0; i < 2; ++i) d2[i * 256 + tid] = s2[i * 256 + tid];
  }
  const int tm = tid >> 4;
  const int tn = tid & 15;
  float acc1[4][4];
  #pragma unroll
  for (int j = 0; j < 4; ++j)
    #pragma unroll
    for (int i = 0; i < 4; ++i) acc1[j][i] = 0.f;

  for (int kh = 0; kh < 2; ++kh) {
    const int k0 = kh << 6;
    const int lr = tid >> 4, lk = (tid & 15) << 2;
    #pragma unroll
    for (int j = 0; j < 4; ++j) {
      int r = lr + (j << 4);
      int rg = row0 + r; rg = rg < n ? rg : n - 1;
      *(float4*)(&Hs[r * 68 + lk]) = *(const float4*)(h + (size_t)rg * H + k0 + lk);
    }
    __syncthreads();
    #pragma unroll 8
    for (int kk = 0; kk < 64; ++kk) {
      float4 w = *(const float4*)(&W1s[(k0 + kk) * 64 + (tn << 2)]);
      #pragma unroll
      for (int j = 0; j < 4; ++j) {
        float a = Hs[(tm + (j << 4)) * 68 + kk];
        acc1[j][0] = fmaf(a, w.x, acc1[j][0]);
        acc1[j][1] = fmaf(a, w.y, acc1[j][1]);
        acc1[j][2] = fmaf(a, w.z, acc1[j][2]);
        acc1[j][3] = fmaf(a, w.w, acc1[j][3]);
      }
    }
    __syncthreads();
  }
  {
    float bb[4]; ld4(bb, b1 + (tn << 2));
    #pragma unroll
    for (int j = 0; j < 4; ++j) {
      int r = tm + (j << 4);
      float hv[4];
      #pragma unroll
      for (int i = 0; i < 4; ++i) hv[i] = fmaxf(acc1[j][i] + bb[i], 0.f);
      st4(&Hs[r * 68 + (tn << 2)], hv);
    }
  }
  __syncthreads();
  const int r2 = tid >> 2;
  const int cg = tid & 3;
  float acc2[8];
  #pragma unroll
  for (int i = 0; i < 8; ++i) acc2[i] = 0.f;
  #pragma unroll 8
  for (int k = 0; k < 64; ++k) {
    float hh = Hs[r2 * 68 + k];
    float4 w0 = *(const float4*)(&W2s[k * 32 + (cg << 3)]);
    float4 w1 = *(const float4*)(&W2s[k * 32 + (cg << 3) + 4]);
    acc2[0] = fmaf(hh, w0.x, acc2[0]);
    acc2[1] = fmaf(hh, w0.y, acc2[1]);
    acc2[2] = fmaf(hh, w0.z, acc2[2]);
    acc2[3] = fmaf(hh, w0.w, acc2[3]);
    acc2[4] = fmaf(hh, w1.x, acc2[4]);
    acc2[5] = fmaf(hh, w1.y, acc2[5]);
    acc2[6] = fmaf(hh, w1.z, acc2[6]);
    acc2[7] = fmaf(hh, w1.w, acc2[7]);
  }
  int rg = row0 + r2;
  if (rg < n) {
    float bb[8]; ld4(bb, b2 + (cg << 3)); ld4(bb + 4, b2 + (cg << 3) + 4);
    float o[8];
    #pragma unroll
    for (int i = 0; i < 8; ++i) o[i] = acc2[i] + bb[i];
    st4(out + (size_t)rg * 32 + (cg << 3), o);
    st4(out + (size_t)rg * 32 + (cg << 3) + 4, o + 4);
  }
}

extern "C" void kernel_launch(void* const* d_in, const int* in_sizes, int n_in,
                              void* d_out, int out_size, void* d_ws, size_t ws_size,
                              hipStream_t stream) {
  const float* x_user     = (const float*)d_in[0];
  const float* x_item     = (const float*)d_in[1];
  const float* enc_W_user = (const float*)d_in[2];
  const float* enc_b_user = (const float*)d_in[3];
  const float* enc_W_item = (const float*)d_in[4];
  const float* enc_b_item = (const float*)d_in[5];
  const float* Wl_ui = (const float*)d_in[6];
  const float* bl_ui = (const float*)d_in[7];
  const float* Wr_ui = (const float*)d_in[8];
  const float* Wl_iu = (const float*)d_in[9];
  const float* bl_iu = (const float*)d_in[10];
  const float* Wr_iu = (const float*)d_in[11];
  const float* bn_g_user = (const float*)d_in[12];
  const float* bn_b_user = (const float*)d_in[13];
  const float* bn_m_user = (const float*)d_in[14];
  const float* bn_v_user = (const float*)d_in[15];
  const float* bn_g_item = (const float*)d_in[16];
  const float* bn_b_item = (const float*)d_in[17];
  const float* bn_m_item = (const float*)d_in[18];
  const float* bn_v_item = (const float*)d_in[19];
  const float* cls_W1 = (const float*)d_in[20];
  const float* cls_b1 = (const float*)d_in[21];
  const float* cls_W2 = (const float*)d_in[22];
  const float* cls_b2 = (const float*)d_in[23];
  const int* ei_ui = (const int*)d_in[24];
  const int* ei_iu = (const int*)d_in[25];

  const int N_ = in_sizes[0] / H;       // 100000
  const int E_ = in_sizes[24] / 2;      // 1600000
  const size_t NH = (size_t)N_ * H;

  // 4 N x H fp32 buffers (204.8 MB) + CSR ints (~14.4 MB) = ~219.2 MB
  float* bufA = (float*)d_ws;           // h_u (encoder), then rotates
  float* bufB = bufA + NH;              // h_i (encoder), then rotates
  float* bufC = bufB + NH;              // spare / agg+new-h
  float* bufD = bufC + NH;              // spare / agg+new-h
  int* ip = (int*)(bufD + NH);
  int* rp_ui  = ip; ip += N_ + 1;
  int* rp_iu  = ip; ip += N_ + 1;
  int* cur_ui = ip; ip += N_;
  int* cur_iu = ip; ip += N_;
  int* col_ui = ip; ip += E_;
  int* col_iu = ip; ip += E_;
  int* part   = ip; ip += 1024;
  int* part2  = ip; ip += 1024;

  const int SB = (N_ + 1023) / 1024;
  const int GB = (N_ + TILE_M - 1) / TILE_M;
  const int EB = (E_ + 255) / 256;
  const int NB = (N_ + 255) / 256;
  const int AB = (N_ + 3) / 4;

  auto build = [&](const int* src, const int* dst, int* cur, int* rp, int* col) {
    zero_int<<<NB, 256, 0, stream>>>(cur, N_);
    edge_hist<<<EB, 256, 0, stream>>>(dst, cur, E_);
    scan_block<<<SB, 1024, 0, stream>>>(cur, rp, part, N_);
    scan_block<<<1, 1024, 0, stream>>>(part, part2, nullptr, SB);
    scan_add<<<SB, 1024, 0, stream>>>(rp, part2, N_, E_);
    copy_int<<<NB, 256, 0, stream>>>(rp, cur, N_);
    edge_fill<<<EB, 256, 0, stream>>>(src, dst, cur, col, E_);
  };
  build(ei_ui, ei_ui + E_, cur_ui, rp_ui, col_ui);
  build(ei_iu, ei_iu + E_, cur_iu, rp_iu, col_iu);

  // encoder
  gemm_fused<<<GB, 256, 0, stream>>>(x_user, enc_W_user, nullptr, nullptr, enc_b_user,
      nullptr, nullptr, nullptr, nullptr, nullptr, bufA, N_, 0);
  gemm_fused<<<GB, 256, 0, stream>>>(x_item, enc_W_item, nullptr, nullptr, enc_b_item,
      nullptr, nullptr, nullptr, nullptr, nullptr, bufB, N_, 0);

  float* hu_c = bufA; float* hi_c = bufB;
  float* sp0 = bufC;  float* sp1 = bufD;
  for (int l = 0; l < 3; ++l) {
    const size_t wo = (size_t)l * H * H;
    const size_t bo = (size_t)l * H;
    // m_user from item->user edges (x_src = h_i); new h_u lands in sp0 (out aliases A1)
    sage_agg<<<AB, 256, 0, stream>>>(hi_c, rp_iu, col_iu, sp0, N_);
    gemm_fused<<<GB, 256, 0, stream>>>(sp0, Wl_iu + wo, hi_c, Wr_iu + wo, bl_iu + bo,
        hu_c, bn_g_user + bo, bn_b_user + bo, bn_m_user + bo, bn_v_user + bo, sp0, N_, 1);
    // m_item from user->item edges (x_src = h_u OLD, still intact in hu_c)
    sage_agg<<<AB, 256, 0, stream>>>(hu_c, rp_ui, col_ui, sp1, N_);
    gemm_fused<<<GB, 256, 0, stream>>>(sp1, Wl_ui + wo, hu_c, Wr_ui + wo, bl_ui + bo,
        hi_c, bn_g_item + bo, bn_b_item + bo, bn_m_item + bo, bn_v_item + bo, sp1, N_, 1);
    // rotate: new current = sp0/sp1; old current become spares
    float* t0 = hu_c; float* t1 = hi_c;
    hu_c = sp0; hi_c = sp1;
    sp0 = t0; sp1 = t1;
  }

  classifier<<<GB, 256, 0, stream>>>(hu_c, cls_W1, cls_b1, cls_W2, cls_b2,
                                     (float*)d_out, N_);
}

// Round 3
// 1551.089 us; speedup vs baseline: 1.2478x; 1.2478x over previous
//
#include <hip/hip_runtime.h>
#include <cstdint>

#define H 128
#define TILE_M 64

typedef __attribute__((ext_vector_type(8))) short bf16x8;
typedef __attribute__((ext_vector_type(4))) float f32x4;

__device__ __forceinline__ float bf2f(unsigned short u) {
  union { unsigned int i; float f; } v; v.i = ((unsigned int)u) << 16; return v.f;
}
__device__ __forceinline__ unsigned short f2bf(float f) {
  unsigned int x = __float_as_uint(f);
  unsigned int r = (x + 0x7fffu + ((x >> 16) & 1u)) >> 16;   // RNE
  return (unsigned short)r;
}
__device__ __forceinline__ void ld4(float* d, const float* s) {
  float4 v = *(const float4*)s; d[0] = v.x; d[1] = v.y; d[2] = v.z; d[3] = v.w;
}
__device__ __forceinline__ void st4(float* d, const float* s) {
  float4 v; v.x = s[0]; v.y = s[1]; v.z = s[2]; v.w = s[3]; *(float4*)d = v;
}

// ---------------- weight transpose+convert: Wt[n][k] = bf16(W[k][n]) ----------------
struct WPtrs { const float* s[14]; unsigned short* d[14]; };

__global__ __launch_bounds__(256)
void conv_w(WPtrs p) {
  int m = blockIdx.y;
  int t = blockIdx.x * 256 + threadIdx.x;    // t = n*128 + k
  int nn = t >> 7, kk = t & 127;
  p.d[m][t] = f2bf(p.s[m][kk * 128 + nn]);
}

// ---------------- CSR build ----------------
__global__ __launch_bounds__(256)
void zero_int(int* __restrict__ p, int n) {
  int i = blockIdx.x * blockDim.x + threadIdx.x;
  if (i < n) p[i] = 0;
}

__global__ __launch_bounds__(256)
void edge_hist(const int* __restrict__ dst, int* __restrict__ deg, int e) {
  int i = blockIdx.x * blockDim.x + threadIdx.x;
  if (i < e) atomicAdd(&deg[dst[i]], 1);
}

__global__ __launch_bounds__(1024)
void scan_block(const int* __restrict__ in, int* __restrict__ out,
                int* __restrict__ partials, int n) {
  __shared__ int sh[1024];
  int i = blockIdx.x * 1024 + threadIdx.x;
  int v = (i < n) ? in[i] : 0;
  sh[threadIdx.x] = v;
  __syncthreads();
  for (int off = 1; off < 1024; off <<= 1) {
    int t = (threadIdx.x >= (unsigned)off) ? sh[threadIdx.x - off] : 0;
    __syncthreads();
    sh[threadIdx.x] += t;
    __syncthreads();
  }
  if (i < n) out[i] = sh[threadIdx.x] - v;   // exclusive
  if (partials != nullptr && threadIdx.x == 1023) partials[blockIdx.x] = sh[1023];
}

__global__ __launch_bounds__(1024)
void scan_add(int* __restrict__ rp, const int* __restrict__ offs, int n, int total) {
  int i = blockIdx.x * 1024 + threadIdx.x;
  if (i < n) rp[i] += offs[blockIdx.x];
  if (i == 0) rp[n] = total;
}

__global__ __launch_bounds__(256)
void copy_int(const int* __restrict__ a, int* __restrict__ b, int n) {
  int i = blockIdx.x * blockDim.x + threadIdx.x;
  if (i < n) b[i] = a[i];
}

__global__ __launch_bounds__(256)
void edge_fill(const int* __restrict__ src, const int* __restrict__ dst,
               int* __restrict__ cur, int* __restrict__ col, int e) {
  int i = blockIdx.x * blockDim.x + threadIdx.x;
  if (i < e) {
    int p = atomicAdd(&cur[dst[i]], 1);
    col[p] = src[i];
  }
}

// ---------------- CSR mean aggregation (bf16): one wave per dst row ----------------
// lane owns elements 2*lane, 2*lane+1 (one 4B load per src row; wave reads full 256B row)
__global__ __launch_bounds__(256)
void sage_agg_bf(const unsigned short* __restrict__ h, const int* __restrict__ rp,
                 const int* __restrict__ col, unsigned short* __restrict__ out, int n) {
  int row = blockIdx.x * 4 + (threadIdx.x >> 6);
  if (row >= n) return;
  int lane = threadIdx.x & 63;
  int beg = rp[row], end = rp[row + 1];
  float sx = 0.f, sy = 0.f;
  int j = beg;
  for (; j + 4 <= end; j += 4) {
    int s0 = col[j], s1 = col[j + 1], s2 = col[j + 2], s3 = col[j + 3];
    unsigned int v0 = *(const unsigned int*)(h + (size_t)s0 * H + lane * 2);
    unsigned int v1 = *(const unsigned int*)(h + (size_t)s1 * H + lane * 2);
    unsigned int v2 = *(const unsigned int*)(h + (size_t)s2 * H + lane * 2);
    unsigned int v3 = *(const unsigned int*)(h + (size_t)s3 * H + lane * 2);
    sx += bf2f(v0 & 0xffff) + bf2f(v1 & 0xffff) + bf2f(v2 & 0xffff) + bf2f(v3 & 0xffff);
    sy += bf2f(v0 >> 16) + bf2f(v1 >> 16) + bf2f(v2 >> 16) + bf2f(v3 >> 16);
  }
  for (; j < end; ++j) {
    unsigned int v0 = *(const unsigned int*)(h + (size_t)col[j] * H + lane * 2);
    sx += bf2f(v0 & 0xffff);
    sy += bf2f(v0 >> 16);
  }
  int c = end - beg;
  float inv = 1.0f / (float)(c > 1 ? c : 1);
  unsigned int o = (unsigned int)f2bf(sx * inv) | ((unsigned int)f2bf(sy * inv) << 16);
  *(unsigned int*)(out + (size_t)row * H + lane * 2) = o;
}

// ---------------- MFMA GEMM (bf16 in, bf16 out, fp32 accumulate) ----------------
// mode 0 (encoder): out = relu(A1f(fp32) @ W1 + bias)
// mode 1 (update):  m = rownorm(A1@W1 + A2@W2 + bias); out = relu(bn(m + resid))
// Block 256 = 4 waves; wave handles 16 rows x 128 cols; 8 n-tiles of 16x16x32 MFMA.
// A-frag: A[m=lane&15][k=quad*8+j]; B-frag: B[k=quad*8+j][n=lane&15] from Wt[n][k].
// C/D: col=lane&15, row=quad*4+reg.  out may alias A1 (block touches only its own rows).
__global__ __launch_bounds__(256)
void gemm_mfma(const unsigned short* A1, const float* A1f,
               const unsigned short* __restrict__ Wt1,
               const unsigned short* A2, const unsigned short* __restrict__ Wt2,
               const float* __restrict__ bias, const unsigned short* resid,
               const float* __restrict__ bng, const float* __restrict__ bnb,
               const float* __restrict__ bnm, const float* __restrict__ bnv,
               unsigned short* out, int n, int mode) {
  const int lane = threadIdx.x & 63;
  const int wv = threadIdx.x >> 6;
  const int c = lane & 15;
  const int q = lane >> 4;
  const int wrow0 = blockIdx.x * 64 + wv * 16;
  int arow = wrow0 + c; if (arow >= n) arow = n - 1;

  f32x4 acc[8];
  #pragma unroll
  for (int t = 0; t < 8; ++t) acc[t] = (f32x4){0.f, 0.f, 0.f, 0.f};

  if (mode == 0) {
    const float* Af = A1f + (size_t)arow * H + q * 8;
    const unsigned short* wb = Wt1 + c * H + q * 8;
    #pragma unroll
    for (int ks = 0; ks < 4; ++ks) {
      float4 x0 = *(const float4*)(Af + ks * 32);
      float4 x1 = *(const float4*)(Af + ks * 32 + 4);
      bf16x8 a;
      a[0] = (short)f2bf(x0.x); a[1] = (short)f2bf(x0.y);
      a[2] = (short)f2bf(x0.z); a[3] = (short)f2bf(x0.w);
      a[4] = (short)f2bf(x1.x); a[5] = (short)f2bf(x1.y);
      a[6] = (short)f2bf(x1.z); a[7] = (short)f2bf(x1.w);
      #pragma unroll
      for (int t = 0; t < 8; ++t) {
        bf16x8 b = *(const bf16x8*)(wb + t * 16 * H + ks * 32);
        acc[t] = __builtin_amdgcn_mfma_f32_16x16x32_bf16(a, b, acc[t], 0, 0, 0);
      }
    }
  } else {
    #pragma unroll
    for (int p = 0; p < 2; ++p) {
      const unsigned short* A = p ? A2 : A1;
      const unsigned short* Wt = p ? Wt2 : Wt1;
      const unsigned short* ab = A + (size_t)arow * H + q * 8;
      const unsigned short* wb = Wt + c * H + q * 8;
      #pragma unroll
      for (int ks = 0; ks < 4; ++ks) {
        bf16x8 a = *(const bf16x8*)(ab + ks * 32);
        #pragma unroll
        for (int t = 0; t < 8; ++t) {
          bf16x8 b = *(const bf16x8*)(wb + t * 16 * H + ks * 32);
          acc[t] = __builtin_amdgcn_mfma_f32_16x16x32_bf16(a, b, acc[t], 0, 0, 0);
        }
      }
    }
  }

  float bia[8];
  #pragma unroll
  for (int t = 0; t < 8; ++t) bia[t] = bias[t * 16 + c];

  if (mode == 0) {
    #pragma unroll
    for (int r = 0; r < 4; ++r) {
      int row = wrow0 + q * 4 + r;
      if (row < n) {
        #pragma unroll
        for (int t = 0; t < 8; ++t) {
          float v = fmaxf(acc[t][r] + bia[t], 0.f);
          out[(size_t)row * H + t * 16 + c] = f2bf(v);
        }
      }
    }
  } else {
    float sg[8], ofs[8];
    #pragma unroll
    for (int t = 0; t < 8; ++t) {
      int cc = t * 16 + c;
      float s = rsqrtf(bnv[cc] + 1e-5f) * bng[cc];
      sg[t] = s;
      ofs[t] = bnb[cc] - bnm[cc] * s;
    }
    float o[8][4];
    float ss[4] = {0.f, 0.f, 0.f, 0.f};
    #pragma unroll
    for (int t = 0; t < 8; ++t)
      #pragma unroll
      for (int r = 0; r < 4; ++r) {
        float v = acc[t][r] + bia[t];
        o[t][r] = v;
        ss[r] = fmaf(v, v, ss[r]);
      }
    #pragma unroll
    for (int r = 0; r < 4; ++r) {
      ss[r] += __shfl_xor(ss[r], 1);
      ss[r] += __shfl_xor(ss[r], 2);
      ss[r] += __shfl_xor(ss[r], 4);
      ss[r] += __shfl_xor(ss[r], 8);
    }
    #pragma unroll
    for (int r = 0; r < 4; ++r) {
      int row = wrow0 + q * 4 + r;
      if (row < n) {
        float inv = 1.0f / fmaxf(sqrtf(ss[r]), 1e-12f);
        #pragma unroll
        for (int t = 0; t < 8; ++t) {
          float rr = bf2f(resid[(size_t)row * H + t * 16 + c]);
          float y = fmaf(o[t][r], inv, rr);
          y = fmaxf(fmaf(y, sg[t], ofs[t]), 0.f);
          out[(size_t)row * H + t * 16 + c] = f2bf(y);
        }
      }
    }
  }
}

// ---------------- fused classifier: out = relu(h@W1+b1)@W2 + b2 (h is bf16) ----------
__global__ __launch_bounds__(256)
void classifier(const unsigned short* __restrict__ h, const float* __restrict__ W1,
                const float* __restrict__ b1, const float* __restrict__ W2,
                const float* __restrict__ b2, float* __restrict__ out, int n) {
  __shared__ float W1s[128 * 64];  // 32 KB
  __shared__ float W2s[64 * 32];   // 8 KB
  __shared__ float Hs[64 * 68];    // A tile, then hid tile
  const int tid = threadIdx.x;
  const int row0 = blockIdx.x * 64;
  {
    const float4* s = (const float4*)W1;
    float4* d = (float4*)W1s;
    #pragma unroll
    for (int i = 0; i < 8; ++i) d[i * 256 + tid] = s[i * 256 + tid];
    const float4* s2 = (const float4*)W2;
    float4* d2 = (float4*)W2s;
    #pragma unroll
    for (int i = 0; i < 2; ++i) d2[i * 256 + tid] = s2[i * 256 + tid];
  }
  const int tm = tid >> 4;
  const int tn = tid & 15;
  float acc1[4][4];
  #pragma unroll
  for (int j = 0; j < 4; ++j)
    #pragma unroll
    for (int i = 0; i < 4; ++i) acc1[j][i] = 0.f;

  for (int kh = 0; kh < 2; ++kh) {
    const int k0 = kh << 6;
    const int lr = tid >> 4, lk = (tid & 15) << 2;
    #pragma unroll
    for (int j = 0; j < 4; ++j) {
      int r = lr + (j << 4);
      int rg = row0 + r; rg = rg < n ? rg : n - 1;
      ushort4 v = *(const ushort4*)(h + (size_t)rg * H + k0 + lk);
      float f[4] = {bf2f(v.x), bf2f(v.y), bf2f(v.z), bf2f(v.w)};
      st4(&Hs[r * 68 + lk], f);
    }
    __syncthreads();
    #pragma unroll 8
    for (int kk = 0; kk < 64; ++kk) {
      float4 w = *(const float4*)(&W1s[(k0 + kk) * 64 + (tn << 2)]);
      #pragma unroll
      for (int j = 0; j < 4; ++j) {
        float a = Hs[(tm + (j << 4)) * 68 + kk];
        acc1[j][0] = fmaf(a, w.x, acc1[j][0]);
        acc1[j][1] = fmaf(a, w.y, acc1[j][1]);
        acc1[j][2] = fmaf(a, w.z, acc1[j][2]);
        acc1[j][3] = fmaf(a, w.w, acc1[j][3]);
      }
    }
    __syncthreads();
  }
  {
    float bb[4]; ld4(bb, b1 + (tn << 2));
    #pragma unroll
    for (int j = 0; j < 4; ++j) {
      int r = tm + (j << 4);
      float hv[4];
      #pragma unroll
      for (int i = 0; i < 4; ++i) hv[i] = fmaxf(acc1[j][i] + bb[i], 0.f);
      st4(&Hs[r * 68 + (tn << 2)], hv);
    }
  }
  __syncthreads();
  const int r2 = tid >> 2;
  const int cg = tid & 3;
  float acc2[8];
  #pragma unroll
  for (int i = 0; i < 8; ++i) acc2[i] = 0.f;
  #pragma unroll 8
  for (int k = 0; k < 64; ++k) {
    float hh = Hs[r2 * 68 + k];
    float4 w0 = *(const float4*)(&W2s[k * 32 + (cg << 3)]);
    float4 w1 = *(const float4*)(&W2s[k * 32 + (cg << 3) + 4]);
    acc2[0] = fmaf(hh, w0.x, acc2[0]);
    acc2[1] = fmaf(hh, w0.y, acc2[1]);
    acc2[2] = fmaf(hh, w0.z, acc2[2]);
    acc2[3] = fmaf(hh, w0.w, acc2[3]);
    acc2[4] = fmaf(hh, w1.x, acc2[4]);
    acc2[5] = fmaf(hh, w1.y, acc2[5]);
    acc2[6] = fmaf(hh, w1.z, acc2[6]);
    acc2[7] = fmaf(hh, w1.w, acc2[7]);
  }
  int rg = row0 + r2;
  if (rg < n) {
    float bb[8]; ld4(bb, b2 + (cg << 3)); ld4(bb + 4, b2 + (cg << 3) + 4);
    float o[8];
    #pragma unroll
    for (int i = 0; i < 8; ++i) o[i] = acc2[i] + bb[i];
    st4(out + (size_t)rg * 32 + (cg << 3), o);
    st4(out + (size_t)rg * 32 + (cg << 3) + 4, o + 4);
  }
}

extern "C" void kernel_launch(void* const* d_in, const int* in_sizes, int n_in,
                              void* d_out, int out_size, void* d_ws, size_t ws_size,
                              hipStream_t stream) {
  const float* x_user     = (const float*)d_in[0];
  const float* x_item     = (const float*)d_in[1];
  const float* enc_W_user = (const float*)d_in[2];
  const float* enc_b_user = (const float*)d_in[3];
  const float* enc_W_item = (const float*)d_in[4];
  const float* enc_b_item = (const float*)d_in[5];
  const float* Wl_ui = (const float*)d_in[6];
  const float* bl_ui = (const float*)d_in[7];
  const float* Wr_ui = (const float*)d_in[8];
  const float* Wl_iu = (const float*)d_in[9];
  const float* bl_iu = (const float*)d_in[10];
  const float* Wr_iu = (const float*)d_in[11];
  const float* bn_g_user = (const float*)d_in[12];
  const float* bn_b_user = (const float*)d_in[13];
  const float* bn_m_user = (const float*)d_in[14];
  const float* bn_v_user = (const float*)d_in[15];
  const float* bn_g_item = (const float*)d_in[16];
  const float* bn_b_item = (const float*)d_in[17];
  const float* bn_m_item = (const float*)d_in[18];
  const float* bn_v_item = (const float*)d_in[19];
  const float* cls_W1 = (const float*)d_in[20];
  const float* cls_b1 = (const float*)d_in[21];
  const float* cls_W2 = (const float*)d_in[22];
  const float* cls_b2 = (const float*)d_in[23];
  const int* ei_ui = (const int*)d_in[24];
  const int* ei_iu = (const int*)d_in[25];

  const int N_ = in_sizes[0] / H;       // 100000
  const int E_ = in_sizes[24] / 2;      // 1600000
  const size_t NH = (size_t)N_ * H;

  // 4 bf16 N x H buffers (102.4 MB) + bf16 W^T (0.46 MB) + CSR ints (~14.4 MB)
  unsigned short* bufA = (unsigned short*)d_ws;
  unsigned short* bufB = bufA + NH;
  unsigned short* bufC = bufB + NH;
  unsigned short* bufD = bufC + NH;
  unsigned short* wt   = bufD + NH;     // 14 x 128 x 128
  int* ip = (int*)(wt + 14 * 16384);
  int* rp_ui  = ip; ip += N_ + 1;
  int* rp_iu  = ip; ip += N_ + 1;
  int* cur_ui = ip; ip += N_;
  int* cur_iu = ip; ip += N_;
  int* col_ui = ip; ip += E_;
  int* col_iu = ip; ip += E_;
  int* part   = ip; ip += 1024;
  int* part2  = ip; ip += 1024;

  // wt layout: 0 enc_u, 1 enc_i, 2+l Wl_ui, 5+l Wr_ui, 8+l Wl_iu, 11+l Wr_iu
  WPtrs wp;
  wp.s[0] = enc_W_user; wp.s[1] = enc_W_item;
  for (int l = 0; l < 3; ++l) {
    wp.s[2 + l]  = Wl_ui + (size_t)l * H * H;
    wp.s[5 + l]  = Wr_ui + (size_t)l * H * H;
    wp.s[8 + l]  = Wl_iu + (size_t)l * H * H;
    wp.s[11 + l] = Wr_iu + (size_t)l * H * H;
  }
  for (int m = 0; m < 14; ++m) wp.d[m] = wt + (size_t)m * 16384;
  conv_w<<<dim3(64, 14), 256, 0, stream>>>(wp);

  const int SB = (N_ + 1023) / 1024;
  const int GB = (N_ + TILE_M - 1) / TILE_M;
  const int EB = (E_ + 255) / 256;
  const int NB = (N_ + 255) / 256;
  const int AB = (N_ + 3) / 4;

  auto build = [&](const int* src, const int* dst, int* cur, int* rp, int* col) {
    zero_int<<<NB, 256, 0, stream>>>(cur, N_);
    edge_hist<<<EB, 256, 0, stream>>>(dst, cur, E_);
    scan_block<<<SB, 1024, 0, stream>>>(cur, rp, part, N_);
    scan_block<<<1, 1024, 0, stream>>>(part, part2, nullptr, SB);
    scan_add<<<SB, 1024, 0, stream>>>(rp, part2, N_, E_);
    copy_int<<<NB, 256, 0, stream>>>(rp, cur, N_);
    edge_fill<<<EB, 256, 0, stream>>>(src, dst, cur, col, E_);
  };
  build(ei_ui, ei_ui + E_, cur_ui, rp_ui, col_ui);
  build(ei_iu, ei_iu + E_, cur_iu, rp_iu, col_iu);

  // encoder (reads fp32 x directly, converts in-register)
  gemm_mfma<<<GB, 256, 0, stream>>>(nullptr, x_user, wt + 0 * 16384,
      nullptr, nullptr, enc_b_user, nullptr, nullptr, nullptr, nullptr, nullptr,
      bufA, N_, 0);
  gemm_mfma<<<GB, 256, 0, stream>>>(nullptr, x_item, wt + 1 * 16384,
      nullptr, nullptr, enc_b_item, nullptr, nullptr, nullptr, nullptr, nullptr,
      bufB, N_, 0);

  unsigned short* hu_c = bufA; unsigned short* hi_c = bufB;
  unsigned short* sp0 = bufC;  unsigned short* sp1 = bufD;
  for (int l = 0; l < 3; ++l) {
    const size_t bo = (size_t)l * H;
    // m_user from item->user edges (x_src = h_i); new h_u lands in sp0 (out aliases A1)
    sage_agg_bf<<<AB, 256, 0, stream>>>(hi_c, rp_iu, col_iu, sp0, N_);
    gemm_mfma<<<GB, 256, 0, stream>>>(sp0, nullptr, wt + (size_t)(8 + l) * 16384,
        hi_c, wt + (size_t)(11 + l) * 16384, bl_iu + bo, hu_c,
        bn_g_user + bo, bn_b_user + bo, bn_m_user + bo, bn_v_user + bo, sp0, N_, 1);
    // m_item from user->item edges (x_src = h_u OLD, still intact in hu_c)
    sage_agg_bf<<<AB, 256, 0, stream>>>(hu_c, rp_ui, col_ui, sp1, N_);
    gemm_mfma<<<GB, 256, 0, stream>>>(sp1, nullptr, wt + (size_t)(2 + l) * 16384,
        hu_c, wt + (size_t)(5 + l) * 16384, bl_ui + bo, hi_c,
        bn_g_item + bo, bn_b_item + bo, bn_m_item + bo, bn_v_item + bo, sp1, N_, 1);
    unsigned short* t0 = hu_c; unsigned short* t1 = hi_c;
    hu_c = sp0; hi_c = sp1;
    sp0 = t0; sp1 = t1;
  }

  classifier<<<GB, 256, 0, stream>>>(hu_c, cls_W1, cls_b1, cls_W2, cls_b2,
                                     (float*)d_out, N_);
}

// Round 4
// 1365.781 us; speedup vs baseline: 1.4171x; 1.1357x over previous
//
#include <hip/hip_runtime.h>
#include <cstdint>

#define H 128
#define BW 128          // bucket node width
#define BSH 7

typedef __attribute__((ext_vector_type(8))) short bf16x8;
typedef __attribute__((ext_vector_type(4))) float f32x4;

__device__ __forceinline__ float bf2f(unsigned short u) {
  union { unsigned int i; float f; } v; v.i = ((unsigned int)u) << 16; return v.f;
}
__device__ __forceinline__ unsigned int f2bf(float f) {
  unsigned int x = __float_as_uint(f);
  return (x + 0x7fffu + ((x >> 16) & 1u)) >> 16;   // RNE
}
__device__ __forceinline__ void ld4(float* d, const float* s) {
  float4 v = *(const float4*)s; d[0] = v.x; d[1] = v.y; d[2] = v.z; d[3] = v.w;
}
__device__ __forceinline__ void st4(float* d, const float* s) {
  float4 v; v.x = s[0]; v.y = s[1]; v.z = s[2]; v.w = s[3]; *(float4*)d = v;
}

// ---------------- weight transpose+convert: Wt[n][k] = bf16(W[k][n]) ----------------
struct WPtrs { const float* s[14]; unsigned short* d[14]; };

__global__ __launch_bounds__(256)
void conv_w(WPtrs p) {
  int m = blockIdx.y;
  int t = blockIdx.x * 256 + threadIdx.x;    // t = n*128 + k
  int nn = t >> 7, kk = t & 127;
  p.d[m][t] = (unsigned short)f2bf(p.s[m][kk * 128 + nn]);
}

__global__ __launch_bounds__(256)
void zero_small(int* __restrict__ p, int n) {
  for (int i = threadIdx.x; i < n; i += 256) p[i] = 0;
}

// ---------------- bucketize edges by dst>>BSH ----------------
// payload: (dst & 127) << 17 | src   (src < 2^17)
__global__ __launch_bounds__(256)
void bucketize(const int* __restrict__ e_ui, const int* __restrict__ e_iu, int E,
               unsigned int* __restrict__ buck, int* __restrict__ gcnt,
               int NBK, int CAP) {
  const int y = blockIdx.y;
  const int* src = y ? e_iu : e_ui;
  const int* dst = src + E;
  unsigned int* bk = buck + (size_t)y * NBK * CAP;
  int* gc = gcnt + y * NBK;
  __shared__ int bin[800];
  __shared__ int res[800];
  const int tid = threadIdx.x;
  for (int i = tid; i < NBK; i += 256) bin[i] = 0;
  __syncthreads();
  unsigned int pay[16]; int meta[16];
  const int base = blockIdx.x * 4096;
  #pragma unroll
  for (int r = 0; r < 16; ++r) {
    int i = base + r * 256 + tid;
    if (i < E) {
      int s = src[i], d = dst[i];
      int b = d >> BSH;
      int lo = atomicAdd(&bin[b], 1);
      pay[r] = ((unsigned int)(d & (BW - 1)) << 17) | (unsigned int)s;
      meta[r] = (b << 12) | lo;
    } else meta[r] = -1;
  }
  __syncthreads();
  for (int i = tid; i < NBK; i += 256) res[i] = atomicAdd(&gc[i], bin[i]);
  __syncthreads();
  #pragma unroll
  for (int r = 0; r < 16; ++r) {
    if (meta[r] >= 0) {
      int b = meta[r] >> 12, lo = meta[r] & 4095;
      int p = res[b] + lo; if (p >= CAP) p = CAP - 1;   // overflow-safe clamp
      bk[(size_t)b * CAP + p] = pay[r];
    }
  }
}

// ---------------- scan bucket counts -> bucket col bases ----------------
__global__ __launch_bounds__(256)
void bucket_scan(const int* __restrict__ gcnt, int* __restrict__ gbase,
                 int* __restrict__ rp_ui, int* __restrict__ rp_iu, int NBK, int E, int N) {
  __shared__ int ts[256];
  const int t = threadIdx.x;
  for (int y = 0; y < 2; ++y) {
    const int* gc = gcnt + y * NBK;
    int* gb = gbase + y * (NBK + 1);
    int v[4]; int s = 0;
    #pragma unroll
    for (int k = 0; k < 4; ++k) { int i = t * 4 + k; v[k] = (i < NBK) ? gc[i] : 0; s += v[k]; }
    ts[t] = s; __syncthreads();
    for (int off = 1; off < 256; off <<= 1) {
      int u = (t >= off) ? ts[t - off] : 0;
      __syncthreads();
      ts[t] += u;
      __syncthreads();
    }
    int excl = ts[t] - s;
    #pragma unroll
    for (int k = 0; k < 4; ++k) { int i = t * 4 + k; if (i < NBK) gb[i] = excl; excl += v[k]; }
    if (t == 255) gb[NBK] = E;
    __syncthreads();
  }
  if (t == 0) { rp_ui[N] = E; rp_iu[N] = E; }
}

// ---------------- per-bucket CSR build (LDS degree+scan+scatter) ----------------
__global__ __launch_bounds__(256)
void csr_build(const unsigned int* __restrict__ buck, const int* __restrict__ gcnt,
               const int* __restrict__ gbase, int* __restrict__ rp_ui, int* __restrict__ rp_iu,
               int* __restrict__ col_ui, int* __restrict__ col_iu, int NBK, int CAP, int N) {
  const int y = blockIdx.y, b = blockIdx.x, t = threadIdx.x;
  const unsigned int* bk = buck + ((size_t)y * NBK + b) * CAP;
  int cnt = gcnt[y * NBK + b];
  if (cnt > CAP) cnt = CAP;
  const int basec = gbase[y * (NBK + 1) + b];
  int* rp = y ? rp_iu : rp_ui;
  int* col = y ? col_iu : col_ui;
  __shared__ int deg[BW], cur[BW];
  if (t < BW) deg[t] = 0;
  __syncthreads();
  for (int j = t; j < cnt; j += 256) atomicAdd(&deg[bk[j] >> 17], 1);
  __syncthreads();
  if (t < BW) cur[t] = deg[t];
  __syncthreads();
  for (int off = 1; off < BW; off <<= 1) {
    int u = (t < BW && t >= off) ? cur[t - off] : 0;
    __syncthreads();
    if (t < BW) cur[t] += u;
    __syncthreads();
  }
  const int lo = b << BSH;
  if (t < BW) {
    int excl = cur[t] - deg[t];
    int node = lo + t;
    if (node < N) rp[node] = basec + excl;
    cur[t] = excl;
  }
  __syncthreads();
  for (int j = t; j < cnt; j += 256) {
    unsigned int u = bk[j];
    int pos = basec + atomicAdd(&cur[u >> 17], 1);
    col[pos] = (int)(u & 0x1FFFFu);
  }
}

// ---------------- encoder GEMM: out = bf16(relu(x @ W + b)) ----------------
struct EncArgs {
  const float* x[2];
  const unsigned short* wt[2];
  const float* b[2];
  unsigned short* out[2];
};

__global__ __launch_bounds__(256)
void enc_gemm(EncArgs a, int n) {
  const int y = blockIdx.y;
  const int tid = threadIdx.x;
  const int lane = tid & 63, wv = tid >> 6;
  const int c = lane & 15, q = lane >> 4;
  const int row0 = blockIdx.x * 64;
  __shared__ unsigned short As[64 * 136];
  // stage x rows (fp32 -> bf16) into LDS
  const float* x = a.x[y];
  #pragma unroll
  for (int k = 0; k < 8; ++k) {
    int idx = k * 256 + tid;           // float4 id
    int r = idx >> 5;                  // 32 float4 per row
    int cc = (idx & 31) * 4;
    int rg = row0 + r; if (rg >= n) rg = n - 1;
    float4 v = *(const float4*)(x + (size_t)rg * H + cc);
    ushort4 o;
    o.x = (unsigned short)f2bf(v.x); o.y = (unsigned short)f2bf(v.y);
    o.z = (unsigned short)f2bf(v.z); o.w = (unsigned short)f2bf(v.w);
    *(ushort4*)&As[r * 136 + cc] = o;
  }
  __syncthreads();
  f32x4 acc[8];
  #pragma unroll
  for (int t = 0; t < 8; ++t) acc[t] = (f32x4){0.f, 0.f, 0.f, 0.f};
  const int lr = wv * 16 + c;
  const unsigned short* wb = a.wt[y] + c * H + q * 8;
  #pragma unroll
  for (int ks = 0; ks < 4; ++ks) {
    bf16x8 av = *(const bf16x8*)&As[lr * 136 + q * 8 + ks * 32];
    #pragma unroll
    for (int t = 0; t < 8; ++t) {
      bf16x8 bv = *(const bf16x8*)(wb + t * 16 * H + ks * 32);
      acc[t] = __builtin_amdgcn_mfma_f32_16x16x32_bf16(av, bv, acc[t], 0, 0, 0);
    }
  }
  const int wrow0 = row0 + wv * 16;
  unsigned short* out = a.out[y];
  const float* bias = a.b[y];
  float bia[8];
  #pragma unroll
  for (int t = 0; t < 8; ++t) bia[t] = bias[t * 16 + c];
  #pragma unroll
  for (int r = 0; r < 4; ++r) {
    int row = wrow0 + q * 4 + r;
    if (row < n) {
      #pragma unroll
      for (int t = 0; t < 8; ++t) {
        float v = fmaxf(acc[t][r] + bia[t], 0.f);
        out[(size_t)row * H + t * 16 + c] = (unsigned short)f2bf(v);
      }
    }
  }
}

// ---------------- fused layer: agg(gather-mean) + agg@Wl + x_src@Wr + epilogue ------
struct LayerArgs {
  const unsigned short* gt[2];      // gather table == x_src
  const unsigned short* resid[2];
  const int* rp[2];
  const int* col[2];
  const unsigned short* wl[2];
  const unsigned short* wr[2];
  const float* bias[2];
  const float* bng[2]; const float* bnb[2]; const float* bnm[2]; const float* bnv[2];
  unsigned short* out[2];
};

__global__ __launch_bounds__(256)
void layer_gemm(LayerArgs a, int n) {
  const int y = blockIdx.y;
  const int tid = threadIdx.x;
  const int lane = tid & 63, wv = tid >> 6;
  const int c = lane & 15, q = lane >> 4;
  const int row0 = blockIdx.x * 64;
  const unsigned short* gt = a.gt[y];
  __shared__ unsigned short As[64 * 136];   // mean-aggregated rows (bf16)
  __shared__ unsigned short Xs[64 * 136];   // x_src own rows
  // stage 1: gather + mean into As (wave wv owns local rows wv*16..+15)
  {
    const int* rp = a.rp[y];
    const int* col = a.col[y];
    for (int i = 0; i < 16; ++i) {
      int r = wv * 16 + i;
      int row = row0 + r;
      float sx = 0.f, sy = 0.f;
      if (row < n) {
        int beg = rp[row], end = rp[row + 1];
        int j = beg;
        for (; j + 4 <= end; j += 4) {
          int s0 = col[j], s1 = col[j + 1], s2 = col[j + 2], s3 = col[j + 3];
          unsigned int v0 = *(const unsigned int*)(gt + (size_t)s0 * H + lane * 2);
          unsigned int v1 = *(const unsigned int*)(gt + (size_t)s1 * H + lane * 2);
          unsigned int v2 = *(const unsigned int*)(gt + (size_t)s2 * H + lane * 2);
          unsigned int v3 = *(const unsigned int*)(gt + (size_t)s3 * H + lane * 2);
          sx += bf2f(v0 & 0xffff) + bf2f(v1 & 0xffff) + bf2f(v2 & 0xffff) + bf2f(v3 & 0xffff);
          sy += bf2f(v0 >> 16) + bf2f(v1 >> 16) + bf2f(v2 >> 16) + bf2f(v3 >> 16);
        }
        for (; j < end; ++j) {
          unsigned int v0 = *(const unsigned int*)(gt + (size_t)col[j] * H + lane * 2);
          sx += bf2f(v0 & 0xffff);
          sy += bf2f(v0 >> 16);
        }
        int cdeg = end - beg;
        float inv = 1.0f / (float)(cdeg > 1 ? cdeg : 1);
        sx *= inv; sy *= inv;
      }
      unsigned int o = f2bf(sx) | (f2bf(sy) << 16);
      *(unsigned int*)&As[r * 136 + lane * 2] = o;
    }
  }
  // stage 2: copy own x_src rows into Xs (coalesced 16B loads)
  #pragma unroll
  for (int k = 0; k < 4; ++k) {
    int idx = k * 256 + tid;           // ushort8 id
    int r = idx >> 4;                  // 16 x ushort8 per row
    int cc = (idx & 15) * 8;
    int rg = row0 + r; if (rg >= n) rg = n - 1;
    bf16x8 v = *(const bf16x8*)(gt + (size_t)rg * H + cc);
    *(bf16x8*)&Xs[r * 136 + cc] = v;
  }
  __syncthreads();
  // stage 3: MFMA  (acc = As@Wl + Xs@Wr)
  f32x4 acc[8];
  #pragma unroll
  for (int t = 0; t < 8; ++t) acc[t] = (f32x4){0.f, 0.f, 0.f, 0.f};
  const int lr = wv * 16 + c;
  {
    const unsigned short* wb = a.wl[y] + c * H + q * 8;
    #pragma unroll
    for (int ks = 0; ks < 4; ++ks) {
      bf16x8 av = *(const bf16x8*)&As[lr * 136 + q * 8 + ks * 32];
      #pragma unroll
      for (int t = 0; t < 8; ++t) {
        bf16x8 bv = *(const bf16x8*)(wb + t * 16 * H + ks * 32);
        acc[t] = __builtin_amdgcn_mfma_f32_16x16x32_bf16(av, bv, acc[t], 0, 0, 0);
      }
    }
  }
  {
    const unsigned short* wb = a.wr[y] + c * H + q * 8;
    #pragma unroll
    for (int ks = 0; ks < 4; ++ks) {
      bf16x8 av = *(const bf16x8*)&Xs[lr * 136 + q * 8 + ks * 32];
      #pragma unroll
      for (int t = 0; t < 8; ++t) {
        bf16x8 bv = *(const bf16x8*)(wb + t * 16 * H + ks * 32);
        acc[t] = __builtin_amdgcn_mfma_f32_16x16x32_bf16(av, bv, acc[t], 0, 0, 0);
      }
    }
  }
  // stage 4: epilogue — bias, rownorm, +resid, BN, relu, store bf16
  const int wrow0 = row0 + wv * 16;
  float bia[8], sg[8], ofs[8];
  {
    const float* bias = a.bias[y];
    const float* bng = a.bng[y]; const float* bnb = a.bnb[y];
    const float* bnm = a.bnm[y]; const float* bnv = a.bnv[y];
    #pragma unroll
    for (int t = 0; t < 8; ++t) {
      int cc = t * 16 + c;
      bia[t] = bias[cc];
      float s = rsqrtf(bnv[cc] + 1e-5f) * bng[cc];
      sg[t] = s;
      ofs[t] = bnb[cc] - bnm[cc] * s;
    }
  }
  float o[8][4];
  float ss[4] = {0.f, 0.f, 0.f, 0.f};
  #pragma unroll
  for (int t = 0; t < 8; ++t)
    #pragma unroll
    for (int r = 0; r < 4; ++r) {
      float v = acc[t][r] + bia[t];
      o[t][r] = v;
      ss[r] = fmaf(v, v, ss[r]);
    }
  #pragma unroll
  for (int r = 0; r < 4; ++r) {
    ss[r] += __shfl_xor(ss[r], 1);
    ss[r] += __shfl_xor(ss[r], 2);
    ss[r] += __shfl_xor(ss[r], 4);
    ss[r] += __shfl_xor(ss[r], 8);
  }
  const unsigned short* resid = a.resid[y];
  unsigned short* out = a.out[y];
  #pragma unroll
  for (int r = 0; r < 4; ++r) {
    int row = wrow0 + q * 4 + r;
    if (row < n) {
      float inv = 1.0f / fmaxf(sqrtf(ss[r]), 1e-12f);
      #pragma unroll
      for (int t = 0; t < 8; ++t) {
        float rr = bf2f(resid[(size_t)row * H + t * 16 + c]);
        float v = fmaf(o[t][r], inv, rr);
        v = fmaxf(fmaf(v, sg[t], ofs[t]), 0.f);
        out[(size_t)row * H + t * 16 + c] = (unsigned short)f2bf(v);
      }
    }
  }
}

// ---------------- fused classifier: out = relu(h@W1+b1)@W2 + b2 (h is bf16) ----------
__global__ __launch_bounds__(256)
void classifier(const unsigned short* __restrict__ h, const float* __restrict__ W1,
                const float* __restrict__ b1, const float* __restrict__ W2,
                const float* __restrict__ b2, float* __restrict__ out, int n) {
  __shared__ float W1s[128 * 64];
  __shared__ float W2s[64 * 32];
  __shared__ float Hs[64 * 68];
  const int tid = threadIdx.x;
  const int row0 = blockIdx.x * 64;
  {
    const float4* s = (const float4*)W1;
    float4* d = (float4*)W1s;
    #pragma unroll
    for (int i = 0; i < 8; ++i) d[i * 256 + tid] = s[i * 256 + tid];
    const float4* s2 = (const float4*)W2;
    float4* d2 = (float4*)W2s;
    #pragma unroll
    for (int i = 0; i < 2; ++i) d2[i * 256 + tid] = s2[i * 256 + tid];
  }
  const int tm = tid >> 4;
  const int tn = tid & 15;
  float acc1[4][4];
  #pragma unroll
  for (int j = 0; j < 4; ++j)
    #pragma unroll
    for (int i = 0; i < 4; ++i) acc1[j][i] = 0.f;

  for (int kh = 0; kh < 2; ++kh) {
    const int k0 = kh << 6;
    const int lr = tid >> 4, lk = (tid & 15) << 2;
    #pragma unroll
    for (int j = 0; j < 4; ++j) {
      int r = lr + (j << 4);
      int rg = row0 + r; rg = rg < n ? rg : n - 1;
      ushort4 v = *(const ushort4*)(h + (size_t)rg * H + k0 + lk);
      float f[4] = {bf2f(v.x), bf2f(v.y), bf2f(v.z), bf2f(v.w)};
      st4(&Hs[r * 68 + lk], f);
    }
    __syncthreads();
    #pragma unroll 8
    for (int kk = 0; kk < 64; ++kk) {
      float4 w = *(const float4*)(&W1s[(k0 + kk) * 64 + (tn << 2)]);
      #pragma unroll
      for (int j = 0; j < 4; ++j) {
        float aa = Hs[(tm + (j << 4)) * 68 + kk];
        acc1[j][0] = fmaf(aa, w.x, acc1[j][0]);
        acc1[j][1] = fmaf(aa, w.y, acc1[j][1]);
        acc1[j][2] = fmaf(aa, w.z, acc1[j][2]);
        acc1[j][3] = fmaf(aa, w.w, acc1[j][3]);
      }
    }
    __syncthreads();
  }
  {
    float bb[4]; ld4(bb, b1 + (tn << 2));
    #pragma unroll
    for (int j = 0; j < 4; ++j) {
      int r = tm + (j << 4);
      float hv[4];
      #pragma unroll
      for (int i = 0; i < 4; ++i) hv[i] = fmaxf(acc1[j][i] + bb[i], 0.f);
      st4(&Hs[r * 68 + (tn << 2)], hv);
    }
  }
  __syncthreads();
  const int r2 = tid >> 2;
  const int cg = tid & 3;
  float acc2[8];
  #pragma unroll
  for (int i = 0; i < 8; ++i) acc2[i] = 0.f;
  #pragma unroll 8
  for (int k = 0; k < 64; ++k) {
    float hh = Hs[r2 * 68 + k];
    float4 w0 = *(const float4*)(&W2s[k * 32 + (cg << 3)]);
    float4 w1 = *(const float4*)(&W2s[k * 32 + (cg << 3) + 4]);
    acc2[0] = fmaf(hh, w0.x, acc2[0]);
    acc2[1] = fmaf(hh, w0.y, acc2[1]);
    acc2[2] = fmaf(hh, w0.z, acc2[2]);
    acc2[3] = fmaf(hh, w0.w, acc2[3]);
    acc2[4] = fmaf(hh, w1.x, acc2[4]);
    acc2[5] = fmaf(hh, w1.y, acc2[5]);
    acc2[6] = fmaf(hh, w1.z, acc2[6]);
    acc2[7] = fmaf(hh, w1.w, acc2[7]);
  }
  int rg = row0 + r2;
  if (rg < n) {
    float bb[8]; ld4(bb, b2 + (cg << 3)); ld4(bb + 4, b2 + (cg << 3) + 4);
    float o[8];
    #pragma unroll
    for (int i = 0; i < 8; ++i) o[i] = acc2[i] + bb[i];
    st4(out + (size_t)rg * 32 + (cg << 3), o);
    st4(out + (size_t)rg * 32 + (cg << 3) + 4, o + 4);
  }
}

extern "C" void kernel_launch(void* const* d_in, const int* in_sizes, int n_in,
                              void* d_out, int out_size, void* d_ws, size_t ws_size,
                              hipStream_t stream) {
  const float* x_user     = (const float*)d_in[0];
  const float* x_item     = (const float*)d_in[1];
  const float* enc_W_user = (const float*)d_in[2];
  const float* enc_b_user = (const float*)d_in[3];
  const float* enc_W_item = (const float*)d_in[4];
  const float* enc_b_item = (const float*)d_in[5];
  const float* Wl_ui = (const float*)d_in[6];
  const float* bl_ui = (const float*)d_in[7];
  const float* Wr_ui = (const float*)d_in[8];
  const float* Wl_iu = (const float*)d_in[9];
  const float* bl_iu = (const float*)d_in[10];
  const float* Wr_iu = (const float*)d_in[11];
  const float* bn_g_user = (const float*)d_in[12];
  const float* bn_b_user = (const float*)d_in[13];
  const float* bn_m_user = (const float*)d_in[14];
  const float* bn_v_user = (const float*)d_in[15];
  const float* bn_g_item = (const float*)d_in[16];
  const float* bn_b_item = (const float*)d_in[17];
  const float* bn_m_item = (const float*)d_in[18];
  const float* bn_v_item = (const float*)d_in[19];
  const float* cls_W1 = (const float*)d_in[20];
  const float* cls_b1 = (const float*)d_in[21];
  const float* cls_W2 = (const float*)d_in[22];
  const float* cls_b2 = (const float*)d_in[23];
  const int* ei_ui = (const int*)d_in[24];
  const int* ei_iu = (const int*)d_in[25];

  const int N_ = in_sizes[0] / H;       // 100000
  const int E_ = in_sizes[24] / 2;      // 1600000
  const size_t NH = (size_t)N_ * H;
  const int NBK = (N_ + BW - 1) >> BSH;        // 782
  const int CAP = E_ / NBK + 512;              // ~2558 (mean + ~11 sigma)

  unsigned short* bufA = (unsigned short*)d_ws;
  unsigned short* bufB = bufA + NH;
  unsigned short* bufC = bufB + NH;
  unsigned short* bufD = bufC + NH;
  unsigned short* wt   = bufD + NH;     // 14 x 128 x 128
  int* ip = (int*)(wt + 14 * 16384);
  int* rp_ui  = ip; ip += N_ + 1;
  int* rp_iu  = ip; ip += N_ + 1;
  int* col_ui = ip; ip += E_;
  int* col_iu = ip; ip += E_;
  int* gcnt   = ip; ip += 2 * NBK;
  int* gbase  = ip; ip += 2 * (NBK + 1);
  unsigned int* buck = (unsigned int*)ip;      // 2 * NBK * CAP

  // wt layout: 0 enc_u, 1 enc_i, 2+l Wl_ui, 5+l Wr_ui, 8+l Wl_iu, 11+l Wr_iu
  WPtrs wp;
  wp.s[0] = enc_W_user; wp.s[1] = enc_W_item;
  for (int l = 0; l < 3; ++l) {
    wp.s[2 + l]  = Wl_ui + (size_t)l * H * H;
    wp.s[5 + l]  = Wr_ui + (size_t)l * H * H;
    wp.s[8 + l]  = Wl_iu + (size_t)l * H * H;
    wp.s[11 + l] = Wr_iu + (size_t)l * H * H;
  }
  for (int m = 0; m < 14; ++m) wp.d[m] = wt + (size_t)m * 16384;

  const int GB = (N_ + 63) / 64;

  zero_small<<<1, 256, 0, stream>>>(gcnt, 2 * NBK);
  conv_w<<<dim3(64, 14), 256, 0, stream>>>(wp);
  bucketize<<<dim3((E_ + 4095) / 4096, 2), 256, 0, stream>>>(ei_ui, ei_iu, E_, buck, gcnt, NBK, CAP);
  bucket_scan<<<1, 256, 0, stream>>>(gcnt, gbase, rp_ui, rp_iu, NBK, E_, N_);
  csr_build<<<dim3(NBK, 2), 256, 0, stream>>>(buck, gcnt, gbase, rp_ui, rp_iu, col_ui, col_iu, NBK, CAP, N_);

  EncArgs ea;
  ea.x[0] = x_user; ea.x[1] = x_item;
  ea.wt[0] = wt; ea.wt[1] = wt + 16384;
  ea.b[0] = enc_b_user; ea.b[1] = enc_b_item;
  ea.out[0] = bufA; ea.out[1] = bufB;
  enc_gemm<<<dim3(GB, 2), 256, 0, stream>>>(ea, N_);

  unsigned short* hu_c = bufA; unsigned short* hi_c = bufB;
  unsigned short* sp0 = bufC;  unsigned short* sp1 = bufD;
  for (int l = 0; l < 3; ++l) {
    const size_t bo = (size_t)l * H;
    LayerArgs la;
    // y=0: user update — gather h_i via iu CSR, x_src=h_i, resid=h_u
    la.gt[0] = hi_c; la.resid[0] = hu_c;
    la.rp[0] = rp_iu; la.col[0] = col_iu;
    la.wl[0] = wt + (size_t)(8 + l) * 16384; la.wr[0] = wt + (size_t)(11 + l) * 16384;
    la.bias[0] = bl_iu + bo;
    la.bng[0] = bn_g_user + bo; la.bnb[0] = bn_b_user + bo;
    la.bnm[0] = bn_m_user + bo; la.bnv[0] = bn_v_user + bo;
    la.out[0] = sp0;
    // y=1: item update — gather h_u via ui CSR, x_src=h_u, resid=h_i
    la.gt[1] = hu_c; la.resid[1] = hi_c;
    la.rp[1] = rp_ui; la.col[1] = col_ui;
    la.wl[1] = wt + (size_t)(2 + l) * 16384; la.wr[1] = wt + (size_t)(5 + l) * 16384;
    la.bias[1] = bl_ui + bo;
    la.bng[1] = bn_g_item + bo; la.bnb[1] = bn_b_item + bo;
    la.bnm[1] = bn_m_item + bo; la.bnv[1] = bn_v_item + bo;
    la.out[1] = sp1;
    layer_gemm<<<dim3(GB, 2), 256, 0, stream>>>(la, N_);
    unsigned short* t0 = hu_c; unsigned short* t1 = hi_c;
    hu_c = sp0; hi_c = sp1;
    sp0 = t0; sp1 = t1;
  }

  classifier<<<GB, 256, 0, stream>>>(hu_c, cls_W1, cls_b1, cls_W2, cls_b2,
                                     (float*)d_out, N_);
}

// Round 5
// 1077.358 us; speedup vs baseline: 1.7965x; 1.2677x over previous
//
#include <hip/hip_runtime.h>
#include <cstdint>

#define H 128
#define BW 128          // bucket node width
#define BSH 7

typedef __attribute__((ext_vector_type(8))) short bf16x8;
typedef __attribute__((ext_vector_type(4))) float f32x4;

__device__ __forceinline__ float bf2f(unsigned short u) {
  union { unsigned int i; float f; } v; v.i = ((unsigned int)u) << 16; return v.f;
}
__device__ __forceinline__ unsigned int f2bf(float f) {
  unsigned int x = __float_as_uint(f);
  return (x + 0x7fffu + ((x >> 16) & 1u)) >> 16;   // RNE
}
__device__ __forceinline__ void ld4(float* d, const float* s) {
  float4 v = *(const float4*)s; d[0] = v.x; d[1] = v.y; d[2] = v.z; d[3] = v.w;
}
__device__ __forceinline__ void st4(float* d, const float* s) {
  float4 v; v.x = s[0]; v.y = s[1]; v.z = s[2]; v.w = s[3]; *(float4*)d = v;
}

// ---------------- weight transpose+convert: Wt[n][k] = bf16(W[k][n]) ----------------
struct WPtrs { const float* s[14]; unsigned short* d[14]; };

__global__ __launch_bounds__(256)
void conv_w(WPtrs p) {
  int m = blockIdx.y;
  int t = blockIdx.x * 256 + threadIdx.x;    // t = n*128 + k
  int nn = t >> 7, kk = t & 127;
  p.d[m][t] = (unsigned short)f2bf(p.s[m][kk * 128 + nn]);
}

__global__ __launch_bounds__(256)
void zero_small(int* __restrict__ p, int n) {
  for (int i = threadIdx.x; i < n; i += 256) p[i] = 0;
}

// ---------------- bucketize edges by dst>>BSH ----------------
// payload: (dst & 127) << 17 | src   (src < 2^17)
__global__ __launch_bounds__(256)
void bucketize(const int* __restrict__ e_ui, const int* __restrict__ e_iu, int E,
               unsigned int* __restrict__ buck, int* __restrict__ gcnt,
               int NBK, int CAP) {
  const int y = blockIdx.y;
  const int* src = y ? e_iu : e_ui;
  const int* dst = src + E;
  unsigned int* bk = buck + (size_t)y * NBK * CAP;
  int* gc = gcnt + y * NBK;
  __shared__ int bin[800];
  __shared__ int res[800];
  const int tid = threadIdx.x;
  for (int i = tid; i < NBK; i += 256) bin[i] = 0;
  __syncthreads();
  unsigned int pay[16]; int meta[16];
  const int base = blockIdx.x * 4096;
  #pragma unroll
  for (int r = 0; r < 16; ++r) {
    int i = base + r * 256 + tid;
    if (i < E) {
      int s = src[i], d = dst[i];
      int b = d >> BSH;
      int lo = atomicAdd(&bin[b], 1);
      pay[r] = ((unsigned int)(d & (BW - 1)) << 17) | (unsigned int)s;
      meta[r] = (b << 12) | lo;
    } else meta[r] = -1;
  }
  __syncthreads();
  for (int i = tid; i < NBK; i += 256) res[i] = atomicAdd(&gc[i], bin[i]);
  __syncthreads();
  #pragma unroll
  for (int r = 0; r < 16; ++r) {
    if (meta[r] >= 0) {
      int b = meta[r] >> 12, lo = meta[r] & 4095;
      int p = res[b] + lo; if (p >= CAP) p = CAP - 1;   // overflow-safe clamp
      bk[(size_t)b * CAP + p] = pay[r];
    }
  }
}

// ---------------- scan bucket counts -> bucket col bases ----------------
__global__ __launch_bounds__(256)
void bucket_scan(const int* __restrict__ gcnt, int* __restrict__ gbase,
                 int* __restrict__ rp_ui, int* __restrict__ rp_iu, int NBK, int E, int N) {
  __shared__ int ts[256];
  const int t = threadIdx.x;
  for (int y = 0; y < 2; ++y) {
    const int* gc = gcnt + y * NBK;
    int* gb = gbase + y * (NBK + 1);
    int v[4]; int s = 0;
    #pragma unroll
    for (int k = 0; k < 4; ++k) { int i = t * 4 + k; v[k] = (i < NBK) ? gc[i] : 0; s += v[k]; }
    ts[t] = s; __syncthreads();
    for (int off = 1; off < 256; off <<= 1) {
      int u = (t >= off) ? ts[t - off] : 0;
      __syncthreads();
      ts[t] += u;
      __syncthreads();
    }
    int excl = ts[t] - s;
    #pragma unroll
    for (int k = 0; k < 4; ++k) { int i = t * 4 + k; if (i < NBK) gb[i] = excl; excl += v[k]; }
    if (t == 255) gb[NBK] = E;
    __syncthreads();
  }
  if (t == 0) { rp_ui[N] = E; rp_iu[N] = E; }
}

// ---------------- per-bucket CSR build (LDS degree+scan+scatter) ----------------
__global__ __launch_bounds__(256)
void csr_build(const unsigned int* __restrict__ buck, const int* __restrict__ gcnt,
               const int* __restrict__ gbase, int* __restrict__ rp_ui, int* __restrict__ rp_iu,
               int* __restrict__ col_ui, int* __restrict__ col_iu, int NBK, int CAP, int N) {
  const int y = blockIdx.y, b = blockIdx.x, t = threadIdx.x;
  const unsigned int* bk = buck + ((size_t)y * NBK + b) * CAP;
  int cnt = gcnt[y * NBK + b];
  if (cnt > CAP) cnt = CAP;
  const int basec = gbase[y * (NBK + 1) + b];
  int* rp = y ? rp_iu : rp_ui;
  int* col = y ? col_iu : col_ui;
  __shared__ int deg[BW], cur[BW];
  if (t < BW) deg[t] = 0;
  __syncthreads();
  for (int j = t; j < cnt; j += 256) atomicAdd(&deg[bk[j] >> 17], 1);
  __syncthreads();
  if (t < BW) cur[t] = deg[t];
  __syncthreads();
  for (int off = 1; off < BW; off <<= 1) {
    int u = (t < BW && t >= off) ? cur[t - off] : 0;
    __syncthreads();
    if (t < BW) cur[t] += u;
    __syncthreads();
  }
  const int lo = b << BSH;
  if (t < BW) {
    int excl = cur[t] - deg[t];
    int node = lo + t;
    if (node < N) rp[node] = basec + excl;
    cur[t] = excl;
  }
  __syncthreads();
  for (int j = t; j < cnt; j += 256) {
    unsigned int u = bk[j];
    int pos = basec + atomicAdd(&cur[u >> 17], 1);
    col[pos] = (int)(u & 0x1FFFFu);
  }
}

// ---------------- encoder GEMM: out = bf16(relu(x @ W + b)) ----------------
struct EncArgs {
  const float* x[2];
  const unsigned short* wt[2];
  const float* b[2];
  unsigned short* out[2];
};

__global__ __launch_bounds__(256)
void enc_gemm(EncArgs a, int n) {
  const int y = blockIdx.y;
  const int tid = threadIdx.x;
  const int lane = tid & 63, wv = tid >> 6;
  const int c = lane & 15, q = lane >> 4;
  const int row0 = blockIdx.x * 64;
  __shared__ unsigned short As[64 * 136];
  const float* x = a.x[y];
  #pragma unroll
  for (int k = 0; k < 8; ++k) {
    int idx = k * 256 + tid;           // float4 id
    int r = idx >> 5;                  // 32 float4 per row
    int cc = (idx & 31) * 4;
    int rg = row0 + r; if (rg >= n) rg = n - 1;
    float4 v = *(const float4*)(x + (size_t)rg * H + cc);
    ushort4 o;
    o.x = (unsigned short)f2bf(v.x); o.y = (unsigned short)f2bf(v.y);
    o.z = (unsigned short)f2bf(v.z); o.w = (unsigned short)f2bf(v.w);
    *(ushort4*)&As[r * 136 + cc] = o;
  }
  __syncthreads();
  f32x4 acc[8];
  #pragma unroll
  for (int t = 0; t < 8; ++t) acc[t] = (f32x4){0.f, 0.f, 0.f, 0.f};
  const int lr = wv * 16 + c;
  const unsigned short* wb = a.wt[y] + c * H + q * 8;
  #pragma unroll
  for (int ks = 0; ks < 4; ++ks) {
    bf16x8 av = *(const bf16x8*)&As[lr * 136 + q * 8 + ks * 32];
    #pragma unroll
    for (int t = 0; t < 8; ++t) {
      bf16x8 bv = *(const bf16x8*)(wb + t * 16 * H + ks * 32);
      acc[t] = __builtin_amdgcn_mfma_f32_16x16x32_bf16(av, bv, acc[t], 0, 0, 0);
    }
  }
  const int wrow0 = row0 + wv * 16;
  unsigned short* out = a.out[y];
  const float* bias = a.b[y];
  float bia[8];
  #pragma unroll
  for (int t = 0; t < 8; ++t) bia[t] = bias[t * 16 + c];
  #pragma unroll
  for (int r = 0; r < 4; ++r) {
    int row = wrow0 + q * 4 + r;
    if (row < n) {
      #pragma unroll
      for (int t = 0; t < 8; ++t) {
        float v = fmaxf(acc[t][r] + bia[t], 0.f);
        out[(size_t)row * H + t * 16 + c] = (unsigned short)f2bf(v);
      }
    }
  }
}

// ---------------- paired CSR mean aggregation: one wave per dst row, 8-deep MLP ------
struct AggArgs {
  const unsigned short* gt[2];
  const int* rp[2];
  const int* col[2];
  unsigned short* out[2];
};

__global__ __launch_bounds__(256)
void agg_pair(AggArgs a, int n) {
  const int y = blockIdx.y;
  const unsigned short* __restrict__ h = a.gt[y];
  const int* __restrict__ rp = a.rp[y];
  const int* __restrict__ col = a.col[y];
  int row = blockIdx.x * 4 + (threadIdx.x >> 6);
  if (row >= n) return;
  int lane = threadIdx.x & 63;
  int beg = rp[row], end = rp[row + 1];
  float sx = 0.f, sy = 0.f;
  int j = beg;
  for (; j + 8 <= end; j += 8) {
    unsigned int v[8];
    #pragma unroll
    for (int k = 0; k < 8; ++k)
      v[k] = *(const unsigned int*)(h + (size_t)col[j + k] * H + lane * 2);
    #pragma unroll
    for (int k = 0; k < 8; ++k) { sx += bf2f(v[k] & 0xffff); sy += bf2f(v[k] >> 16); }
  }
  for (; j + 2 <= end; j += 2) {
    unsigned int v0 = *(const unsigned int*)(h + (size_t)col[j] * H + lane * 2);
    unsigned int v1 = *(const unsigned int*)(h + (size_t)col[j + 1] * H + lane * 2);
    sx += bf2f(v0 & 0xffff) + bf2f(v1 & 0xffff);
    sy += bf2f(v0 >> 16) + bf2f(v1 >> 16);
  }
  if (j < end) {
    unsigned int v0 = *(const unsigned int*)(h + (size_t)col[j] * H + lane * 2);
    sx += bf2f(v0 & 0xffff);
    sy += bf2f(v0 >> 16);
  }
  int c = end - beg;
  float inv = 1.0f / (float)(c > 1 ? c : 1);
  unsigned int o = f2bf(sx * inv) | (f2bf(sy * inv) << 16);
  *(unsigned int*)(a.out[y] + (size_t)row * H + lane * 2) = o;
}

// ---------------- paired layer GEMM: m = rownorm(Agg@Wl + X@Wr + b); out=relu(bn(m+resid))
// Register-direct MFMA (no LDS, no barriers). out aliases Aagg: each block reads only
// its own 64-row range (clamped reads touch only the last block's own rows) and all
// A-reads precede the epilogue stores in-wave.
struct MMArgs {
  const unsigned short* Aagg[2];
  const unsigned short* Xsrc[2];
  const unsigned short* resid[2];
  const unsigned short* wl[2];
  const unsigned short* wr[2];
  const float* bias[2];
  const float* bng[2]; const float* bnb[2]; const float* bnm[2]; const float* bnv[2];
  unsigned short* out[2];
};

__global__ __launch_bounds__(256)
void layer_mm(MMArgs a, int n) {
  const int y = blockIdx.y;
  const int lane = threadIdx.x & 63;
  const int wv = threadIdx.x >> 6;
  const int c = lane & 15;
  const int q = lane >> 4;
  const int wrow0 = blockIdx.x * 64 + wv * 16;
  int arow = wrow0 + c; if (arow >= n) arow = n - 1;

  f32x4 acc[8];
  #pragma unroll
  for (int t = 0; t < 8; ++t) acc[t] = (f32x4){0.f, 0.f, 0.f, 0.f};

  #pragma unroll
  for (int p = 0; p < 2; ++p) {
    const unsigned short* A = p ? a.Xsrc[y] : a.Aagg[y];
    const unsigned short* Wt = p ? a.wr[y] : a.wl[y];
    const unsigned short* ab = A + (size_t)arow * H + q * 8;
    const unsigned short* wb = Wt + c * H + q * 8;
    #pragma unroll
    for (int ks = 0; ks < 4; ++ks) {
      bf16x8 av = *(const bf16x8*)(ab + ks * 32);
      #pragma unroll
      for (int t = 0; t < 8; ++t) {
        bf16x8 bv = *(const bf16x8*)(wb + t * 16 * H + ks * 32);
        acc[t] = __builtin_amdgcn_mfma_f32_16x16x32_bf16(av, bv, acc[t], 0, 0, 0);
      }
    }
  }

  float bia[8], sg[8], ofs[8];
  {
    const float* bias = a.bias[y];
    const float* bng = a.bng[y]; const float* bnb = a.bnb[y];
    const float* bnm = a.bnm[y]; const float* bnv = a.bnv[y];
    #pragma unroll
    for (int t = 0; t < 8; ++t) {
      int cc = t * 16 + c;
      bia[t] = bias[cc];
      float s = rsqrtf(bnv[cc] + 1e-5f) * bng[cc];
      sg[t] = s;
      ofs[t] = bnb[cc] - bnm[cc] * s;
    }
  }
  float o[8][4];
  float ss[4] = {0.f, 0.f, 0.f, 0.f};
  #pragma unroll
  for (int t = 0; t < 8; ++t)
    #pragma unroll
    for (int r = 0; r < 4; ++r) {
      float v = acc[t][r] + bia[t];
      o[t][r] = v;
      ss[r] = fmaf(v, v, ss[r]);
    }
  #pragma unroll
  for (int r = 0; r < 4; ++r) {
    ss[r] += __shfl_xor(ss[r], 1);
    ss[r] += __shfl_xor(ss[r], 2);
    ss[r] += __shfl_xor(ss[r], 4);
    ss[r] += __shfl_xor(ss[r], 8);
  }
  const unsigned short* resid = a.resid[y];
  unsigned short* out = a.out[y];
  #pragma unroll
  for (int r = 0; r < 4; ++r) {
    int row = wrow0 + q * 4 + r;
    if (row < n) {
      float inv = 1.0f / fmaxf(sqrtf(ss[r]), 1e-12f);
      #pragma unroll
      for (int t = 0; t < 8; ++t) {
        float rr = bf2f(resid[(size_t)row * H + t * 16 + c]);
        float v = fmaf(o[t][r], inv, rr);
        v = fmaxf(fmaf(v, sg[t], ofs[t]), 0.f);
        out[(size_t)row * H + t * 16 + c] = (unsigned short)f2bf(v);
      }
    }
  }
}

// ---------------- fused classifier: out = relu(h@W1+b1)@W2 + b2 (h is bf16) ----------
__global__ __launch_bounds__(256)
void classifier(const unsigned short* __restrict__ h, const float* __restrict__ W1,
                const float* __restrict__ b1, const float* __restrict__ W2,
                const float* __restrict__ b2, float* __restrict__ out, int n) {
  __shared__ float W1s[128 * 64];
  __shared__ float W2s[64 * 32];
  __shared__ float Hs[64 * 68];
  const int tid = threadIdx.x;
  const int row0 = blockIdx.x * 64;
  {
    const float4* s = (const float4*)W1;
    float4* d = (float4*)W1s;
    #pragma unroll
    for (int i = 0; i < 8; ++i) d[i * 256 + tid] = s[i * 256 + tid];
    const float4* s2 = (const float4*)W2;
    float4* d2 = (float4*)W2s;
    #pragma unroll
    for (int i = 0; i < 2; ++i) d2[i * 256 + tid] = s2[i * 256 + tid];
  }
  const int tm = tid >> 4;
  const int tn = tid & 15;
  float acc1[4][4];
  #pragma unroll
  for (int j = 0; j < 4; ++j)
    #pragma unroll
    for (int i = 0; i < 4; ++i) acc1[j][i] = 0.f;

  for (int kh = 0; kh < 2; ++kh) {
    const int k0 = kh << 6;
    const int lr = tid >> 4, lk = (tid & 15) << 2;
    #pragma unroll
    for (int j = 0; j < 4; ++j) {
      int r = lr + (j << 4);
      int rg = row0 + r; rg = rg < n ? rg : n - 1;
      ushort4 v = *(const ushort4*)(h + (size_t)rg * H + k0 + lk);
      float f[4] = {bf2f(v.x), bf2f(v.y), bf2f(v.z), bf2f(v.w)};
      st4(&Hs[r * 68 + lk], f);
    }
    __syncthreads();
    #pragma unroll 8
    for (int kk = 0; kk < 64; ++kk) {
      float4 w = *(const float4*)(&W1s[(k0 + kk) * 64 + (tn << 2)]);
      #pragma unroll
      for (int j = 0; j < 4; ++j) {
        float aa = Hs[(tm + (j << 4)) * 68 + kk];
        acc1[j][0] = fmaf(aa, w.x, acc1[j][0]);
        acc1[j][1] = fmaf(aa, w.y, acc1[j][1]);
        acc1[j][2] = fmaf(aa, w.z, acc1[j][2]);
        acc1[j][3] = fmaf(aa, w.w, acc1[j][3]);
      }
    }
    __syncthreads();
  }
  {
    float bb[4]; ld4(bb, b1 + (tn << 2));
    #pragma unroll
    for (int j = 0; j < 4; ++j) {
      int r = tm + (j << 4);
      float hv[4];
      #pragma unroll
      for (int i = 0; i < 4; ++i) hv[i] = fmaxf(acc1[j][i] + bb[i], 0.f);
      st4(&Hs[r * 68 + (tn << 2)], hv);
    }
  }
  __syncthreads();
  const int r2 = tid >> 2;
  const int cg = tid & 3;
  float acc2[8];
  #pragma unroll
  for (int i = 0; i < 8; ++i) acc2[i] = 0.f;
  #pragma unroll 8
  for (int k = 0; k < 64; ++k) {
    float hh = Hs[r2 * 68 + k];
    float4 w0 = *(const float4*)(&W2s[k * 32 + (cg << 3)]);
    float4 w1 = *(const float4*)(&W2s[k * 32 + (cg << 3) + 4]);
    acc2[0] = fmaf(hh, w0.x, acc2[0]);
    acc2[1] = fmaf(hh, w0.y, acc2[1]);
    acc2[2] = fmaf(hh, w0.z, acc2[2]);
    acc2[3] = fmaf(hh, w0.w, acc2[3]);
    acc2[4] = fmaf(hh, w1.x, acc2[4]);
    acc2[5] = fmaf(hh, w1.y, acc2[5]);
    acc2[6] = fmaf(hh, w1.z, acc2[6]);
    acc2[7] = fmaf(hh, w1.w, acc2[7]);
  }
  int rg = row0 + r2;
  if (rg < n) {
    float bb[8]; ld4(bb, b2 + (cg << 3)); ld4(bb + 4, b2 + (cg << 3) + 4);
    float o[8];
    #pragma unroll
    for (int i = 0; i < 8; ++i) o[i] = acc2[i] + bb[i];
    st4(out + (size_t)rg * 32 + (cg << 3), o);
    st4(out + (size_t)rg * 32 + (cg << 3) + 4, o + 4);
  }
}

extern "C" void kernel_launch(void* const* d_in, const int* in_sizes, int n_in,
                              void* d_out, int out_size, void* d_ws, size_t ws_size,
                              hipStream_t stream) {
  const float* x_user     = (const float*)d_in[0];
  const float* x_item     = (const float*)d_in[1];
  const float* enc_W_user = (const float*)d_in[2];
  const float* enc_b_user = (const float*)d_in[3];
  const float* enc_W_item = (const float*)d_in[4];
  const float* enc_b_item = (const float*)d_in[5];
  const float* Wl_ui = (const float*)d_in[6];
  const float* bl_ui = (const float*)d_in[7];
  const float* Wr_ui = (const float*)d_in[8];
  const float* Wl_iu = (const float*)d_in[9];
  const float* bl_iu = (const float*)d_in[10];
  const float* Wr_iu = (const float*)d_in[11];
  const float* bn_g_user = (const float*)d_in[12];
  const float* bn_b_user = (const float*)d_in[13];
  const float* bn_m_user = (const float*)d_in[14];
  const float* bn_v_user = (const float*)d_in[15];
  const float* bn_g_item = (const float*)d_in[16];
  const float* bn_b_item = (const float*)d_in[17];
  const float* bn_m_item = (const float*)d_in[18];
  const float* bn_v_item = (const float*)d_in[19];
  const float* cls_W1 = (const float*)d_in[20];
  const float* cls_b1 = (const float*)d_in[21];
  const float* cls_W2 = (const float*)d_in[22];
  const float* cls_b2 = (const float*)d_in[23];
  const int* ei_ui = (const int*)d_in[24];
  const int* ei_iu = (const int*)d_in[25];

  const int N_ = in_sizes[0] / H;       // 100000
  const int E_ = in_sizes[24] / 2;      // 1600000
  const size_t NH = (size_t)N_ * H;
  const int NBK = (N_ + BW - 1) >> BSH;        // 782
  const int CAP = E_ / NBK + 512;              // ~2558

  unsigned short* bufA = (unsigned short*)d_ws;
  unsigned short* bufB = bufA + NH;
  unsigned short* bufC = bufB + NH;
  unsigned short* bufD = bufC + NH;
  unsigned short* wt   = bufD + NH;     // 14 x 128 x 128
  int* ip = (int*)(wt + 14 * 16384);
  int* rp_ui  = ip; ip += N_ + 1;
  int* rp_iu  = ip; ip += N_ + 1;
  int* col_ui = ip; ip += E_;
  int* col_iu = ip; ip += E_;
  int* gcnt   = ip; ip += 2 * NBK;
  int* gbase  = ip; ip += 2 * (NBK + 1);
  unsigned int* buck = (unsigned int*)ip;      // 2 * NBK * CAP

  WPtrs wp;
  wp.s[0] = enc_W_user; wp.s[1] = enc_W_item;
  for (int l = 0; l < 3; ++l) {
    wp.s[2 + l]  = Wl_ui + (size_t)l * H * H;
    wp.s[5 + l]  = Wr_ui + (size_t)l * H * H;
    wp.s[8 + l]  = Wl_iu + (size_t)l * H * H;
    wp.s[11 + l] = Wr_iu + (size_t)l * H * H;
  }
  for (int m = 0; m < 14; ++m) wp.d[m] = wt + (size_t)m * 16384;

  const int GB = (N_ + 63) / 64;
  const int AB = (N_ + 3) / 4;

  zero_small<<<1, 256, 0, stream>>>(gcnt, 2 * NBK);
  conv_w<<<dim3(64, 14), 256, 0, stream>>>(wp);
  bucketize<<<dim3((E_ + 4095) / 4096, 2), 256, 0, stream>>>(ei_ui, ei_iu, E_, buck, gcnt, NBK, CAP);
  bucket_scan<<<1, 256, 0, stream>>>(gcnt, gbase, rp_ui, rp_iu, NBK, E_, N_);
  csr_build<<<dim3(NBK, 2), 256, 0, stream>>>(buck, gcnt, gbase, rp_ui, rp_iu, col_ui, col_iu, NBK, CAP, N_);

  EncArgs ea;
  ea.x[0] = x_user; ea.x[1] = x_item;
  ea.wt[0] = wt; ea.wt[1] = wt + 16384;
  ea.b[0] = enc_b_user; ea.b[1] = enc_b_item;
  ea.out[0] = bufA; ea.out[1] = bufB;
  enc_gemm<<<dim3(GB, 2), 256, 0, stream>>>(ea, N_);

  unsigned short* hu_c = bufA; unsigned short* hi_c = bufB;
  unsigned short* sp0 = bufC;  unsigned short* sp1 = bufD;
  for (int l = 0; l < 3; ++l) {
    const size_t bo = (size_t)l * H;
    // aggregation: y=0 gathers h_i via iu CSR -> sp0; y=1 gathers h_u via ui CSR -> sp1
    AggArgs aa;
    aa.gt[0] = hi_c; aa.rp[0] = rp_iu; aa.col[0] = col_iu; aa.out[0] = sp0;
    aa.gt[1] = hu_c; aa.rp[1] = rp_ui; aa.col[1] = col_ui; aa.out[1] = sp1;
    agg_pair<<<dim3(AB, 2), 256, 0, stream>>>(aa, N_);
    // GEMM+epilogue: y=0 user update (out sp0, aliases Aagg), y=1 item update (out sp1)
    MMArgs ma;
    ma.Aagg[0] = sp0; ma.Xsrc[0] = hi_c; ma.resid[0] = hu_c;
    ma.wl[0] = wt + (size_t)(8 + l) * 16384; ma.wr[0] = wt + (size_t)(11 + l) * 16384;
    ma.bias[0] = bl_iu + bo;
    ma.bng[0] = bn_g_user + bo; ma.bnb[0] = bn_b_user + bo;
    ma.bnm[0] = bn_m_user + bo; ma.bnv[0] = bn_v_user + bo;
    ma.out[0] = sp0;
    ma.Aagg[1] = sp1; ma.Xsrc[1] = hu_c; ma.resid[1] = hi_c;
    ma.wl[1] = wt + (size_t)(2 + l) * 16384; ma.wr[1] = wt + (size_t)(5 + l) * 16384;
    ma.bias[1] = bl_ui + bo;
    ma.bng[1] = bn_g_item + bo; ma.bnb[1] = bn_b_item + bo;
    ma.bnm[1] = bn_m_item + bo; ma.bnv[1] = bn_v_item + bo;
    ma.out[1] = sp1;
    layer_mm<<<dim3(GB, 2), 256, 0, stream>>>(ma, N_);
    unsigned short* t0 = hu_c; unsigned short* t1 = hi_c;
    hu_c = sp0; hi_c = sp1;
    sp0 = t0; sp1 = t1;
  }

  classifier<<<GB, 256, 0, stream>>>(hu_c, cls_W1, cls_b1, cls_W2, cls_b2,
                                     (float*)d_out, N_);
}

// Round 6
// 1049.779 us; speedup vs baseline: 1.8437x; 1.0263x over previous
//
#include <hip/hip_runtime.h>
#include <cstdint>

#define H 128
#define BW 128          // bucket node width
#define BSH 7

typedef __attribute__((ext_vector_type(8))) short bf16x8;
typedef __attribute__((ext_vector_type(4))) float f32x4;

__device__ __forceinline__ float bf2f(unsigned short u) {
  union { unsigned int i; float f; } v; v.i = ((unsigned int)u) << 16; return v.f;
}
__device__ __forceinline__ unsigned int f2bf(float f) {
  unsigned int x = __float_as_uint(f);
  return (x + 0x7fffu + ((x >> 16) & 1u)) >> 16;   // RNE
}
__device__ __forceinline__ void ld4(float* d, const float* s) {
  float4 v = *(const float4*)s; d[0] = v.x; d[1] = v.y; d[2] = v.z; d[3] = v.w;
}
__device__ __forceinline__ void st4(float* d, const float* s) {
  float4 v; v.x = s[0]; v.y = s[1]; v.z = s[2]; v.w = s[3]; *(float4*)d = v;
}

// ---------------- weight transpose+convert: Wt[n][k] = bf16(W[k][n]) ----------------
struct WPtrs { const float* s[14]; unsigned short* d[14]; };

__global__ __launch_bounds__(256)
void conv_w(WPtrs p) {
  int m = blockIdx.y;
  int t = blockIdx.x * 256 + threadIdx.x;    // t = n*128 + k
  int nn = t >> 7, kk = t & 127;
  p.d[m][t] = (unsigned short)f2bf(p.s[m][kk * 128 + nn]);
}

__global__ __launch_bounds__(256)
void zero_small(int* __restrict__ p, int n) {
  for (int i = threadIdx.x; i < n; i += 256) p[i] = 0;
}

// ---------------- bucketize edges by dst>>BSH ----------------
// payload: (dst & 127) << 17 | src   (src < 2^17)
__global__ __launch_bounds__(256)
void bucketize(const int* __restrict__ e_ui, const int* __restrict__ e_iu, int E,
               unsigned int* __restrict__ buck, int* __restrict__ gcnt,
               int NBK, int CAP) {
  const int y = blockIdx.y;
  const int* src = y ? e_iu : e_ui;
  const int* dst = src + E;
  unsigned int* bk = buck + (size_t)y * NBK * CAP;
  int* gc = gcnt + y * NBK;
  __shared__ int bin[800];
  __shared__ int res[800];
  const int tid = threadIdx.x;
  for (int i = tid; i < NBK; i += 256) bin[i] = 0;
  __syncthreads();
  unsigned int pay[16]; int meta[16];
  const int base = blockIdx.x * 4096;
  #pragma unroll
  for (int r = 0; r < 16; ++r) {
    int i = base + r * 256 + tid;
    if (i < E) {
      int s = src[i], d = dst[i];
      int b = d >> BSH;
      int lo = atomicAdd(&bin[b], 1);
      pay[r] = ((unsigned int)(d & (BW - 1)) << 17) | (unsigned int)s;
      meta[r] = (b << 12) | lo;
    } else meta[r] = -1;
  }
  __syncthreads();
  for (int i = tid; i < NBK; i += 256) res[i] = atomicAdd(&gc[i], bin[i]);
  __syncthreads();
  #pragma unroll
  for (int r = 0; r < 16; ++r) {
    if (meta[r] >= 0) {
      int b = meta[r] >> 12, lo = meta[r] & 4095;
      int p = res[b] + lo; if (p >= CAP) p = CAP - 1;   // overflow-safe clamp
      bk[(size_t)b * CAP + p] = pay[r];
    }
  }
}

// ---------------- scan bucket counts -> bucket col bases ----------------
__global__ __launch_bounds__(256)
void bucket_scan(const int* __restrict__ gcnt, int* __restrict__ gbase,
                 int* __restrict__ rp_ui, int* __restrict__ rp_iu, int NBK, int E, int N) {
  __shared__ int ts[256];
  const int t = threadIdx.x;
  for (int y = 0; y < 2; ++y) {
    const int* gc = gcnt + y * NBK;
    int* gb = gbase + y * (NBK + 1);
    int v[4]; int s = 0;
    #pragma unroll
    for (int k = 0; k < 4; ++k) { int i = t * 4 + k; v[k] = (i < NBK) ? gc[i] : 0; s += v[k]; }
    ts[t] = s; __syncthreads();
    for (int off = 1; off < 256; off <<= 1) {
      int u = (t >= off) ? ts[t - off] : 0;
      __syncthreads();
      ts[t] += u;
      __syncthreads();
    }
    int excl = ts[t] - s;
    #pragma unroll
    for (int k = 0; k < 4; ++k) { int i = t * 4 + k; if (i < NBK) gb[i] = excl; excl += v[k]; }
    if (t == 255) gb[NBK] = E;
    __syncthreads();
  }
  if (t == 0) { rp_ui[N] = E; rp_iu[N] = E; }
}

// ---------------- per-bucket CSR build (LDS degree+scan+scatter) ----------------
__global__ __launch_bounds__(256)
void csr_build(const unsigned int* __restrict__ buck, const int* __restrict__ gcnt,
               const int* __restrict__ gbase, int* __restrict__ rp_ui, int* __restrict__ rp_iu,
               int* __restrict__ col_ui, int* __restrict__ col_iu, int NBK, int CAP, int N) {
  const int y = blockIdx.y, b = blockIdx.x, t = threadIdx.x;
  const unsigned int* bk = buck + ((size_t)y * NBK + b) * CAP;
  int cnt = gcnt[y * NBK + b];
  if (cnt > CAP) cnt = CAP;
  const int basec = gbase[y * (NBK + 1) + b];
  int* rp = y ? rp_iu : rp_ui;
  int* col = y ? col_iu : col_ui;
  __shared__ int deg[BW], cur[BW];
  if (t < BW) deg[t] = 0;
  __syncthreads();
  for (int j = t; j < cnt; j += 256) atomicAdd(&deg[bk[j] >> 17], 1);
  __syncthreads();
  if (t < BW) cur[t] = deg[t];
  __syncthreads();
  for (int off = 1; off < BW; off <<= 1) {
    int u = (t < BW && t >= off) ? cur[t - off] : 0;
    __syncthreads();
    if (t < BW) cur[t] += u;
    __syncthreads();
  }
  const int lo = b << BSH;
  if (t < BW) {
    int excl = cur[t] - deg[t];
    int node = lo + t;
    if (node < N) rp[node] = basec + excl;
    cur[t] = excl;
  }
  __syncthreads();
  for (int j = t; j < cnt; j += 256) {
    unsigned int u = bk[j];
    int pos = basec + atomicAdd(&cur[u >> 17], 1);
    col[pos] = (int)(u & 0x1FFFFu);
  }
}

// ---------------- encoder GEMM: out = bf16(relu(x @ W + b)) ----------------
struct EncArgs {
  const float* x[2];
  const unsigned short* wt[2];
  const float* b[2];
  unsigned short* out[2];
};

__global__ __launch_bounds__(256)
void enc_gemm(EncArgs a, int n) {
  const int y = blockIdx.y;
  const int tid = threadIdx.x;
  const int lane = tid & 63, wv = tid >> 6;
  const int c = lane & 15, q = lane >> 4;
  const int row0 = blockIdx.x * 64;
  __shared__ unsigned short As[64 * 136];
  const float* x = a.x[y];
  #pragma unroll
  for (int k = 0; k < 8; ++k) {
    int idx = k * 256 + tid;           // float4 id
    int r = idx >> 5;                  // 32 float4 per row
    int cc = (idx & 31) * 4;
    int rg = row0 + r; if (rg >= n) rg = n - 1;
    float4 v = *(const float4*)(x + (size_t)rg * H + cc);
    ushort4 o;
    o.x = (unsigned short)f2bf(v.x); o.y = (unsigned short)f2bf(v.y);
    o.z = (unsigned short)f2bf(v.z); o.w = (unsigned short)f2bf(v.w);
    *(ushort4*)&As[r * 136 + cc] = o;
  }
  __syncthreads();
  f32x4 acc[8];
  #pragma unroll
  for (int t = 0; t < 8; ++t) acc[t] = (f32x4){0.f, 0.f, 0.f, 0.f};
  const int lr = wv * 16 + c;
  const unsigned short* wb = a.wt[y] + c * H + q * 8;
  #pragma unroll
  for (int ks = 0; ks < 4; ++ks) {
    bf16x8 av = *(const bf16x8*)&As[lr * 136 + q * 8 + ks * 32];
    #pragma unroll
    for (int t = 0; t < 8; ++t) {
      bf16x8 bv = *(const bf16x8*)(wb + t * 16 * H + ks * 32);
      acc[t] = __builtin_amdgcn_mfma_f32_16x16x32_bf16(av, bv, acc[t], 0, 0, 0);
    }
  }
  const int wrow0 = row0 + wv * 16;
  unsigned short* out = a.out[y];
  const float* bias = a.b[y];
  float bia[8];
  #pragma unroll
  for (int t = 0; t < 8; ++t) bia[t] = bias[t * 16 + c];
  #pragma unroll
  for (int r = 0; r < 4; ++r) {
    int row = wrow0 + q * 4 + r;
    if (row < n) {
      #pragma unroll
      for (int t = 0; t < 8; ++t) {
        float v = fmaxf(acc[t][r] + bia[t], 0.f);
        out[(size_t)row * H + t * 16 + c] = (unsigned short)f2bf(v);
      }
    }
  }
}

// ---------------- paired CSR mean aggregation ----------------
// quarter-wave per edge: 16 lanes x 16B cover a 256B row; 4 edges per load instr;
// predicated 16-edge batches -> a mean-degree-16 row completes in 1-2 latency rounds.
struct AggArgs {
  const unsigned short* gt[2];
  const int* rp[2];
  const int* col[2];
  unsigned short* out[2];
};

__global__ __launch_bounds__(256)
void agg_pair(AggArgs a, int n) {
  const int y = blockIdx.y;
  const unsigned short* __restrict__ h = a.gt[y];
  const int* __restrict__ rp = a.rp[y];
  const int* __restrict__ col = a.col[y];
  int row = blockIdx.x * 4 + (threadIdx.x >> 6);
  if (row >= n) return;
  const int lane = threadIdx.x & 63;
  const int g = lane >> 4;          // edge group 0..3
  const int c = lane & 15;          // column chunk: cols c*8 .. c*8+7
  const int beg = rp[row], end = rp[row + 1];
  float s[8] = {0.f, 0.f, 0.f, 0.f, 0.f, 0.f, 0.f, 0.f};
  for (int j = beg; j < end; j += 16) {
    bf16x8 v[4]; float m[4];
    #pragma unroll
    for (int u = 0; u < 4; ++u) {
      int idx = j + u * 4 + g;
      int ii = idx < end ? idx : beg;          // always-valid col index
      m[u] = idx < end ? 1.f : 0.f;
      v[u] = *(const bf16x8*)(h + (size_t)col[ii] * H + c * 8);
    }
    #pragma unroll
    for (int u = 0; u < 4; ++u)
      #pragma unroll
      for (int k = 0; k < 8; ++k)
        s[k] = fmaf(m[u], bf2f((unsigned short)v[u][k]), s[k]);
  }
  // combine the 4 edge groups (lanes sharing c)
  #pragma unroll
  for (int k = 0; k < 8; ++k) {
    s[k] += __shfl_xor(s[k], 16);
    s[k] += __shfl_xor(s[k], 32);
  }
  int cdeg = end - beg;
  float inv = 1.0f / (float)(cdeg > 1 ? cdeg : 1);
  if (g == 0) {
    bf16x8 o;
    #pragma unroll
    for (int k = 0; k < 8; ++k) o[k] = (short)(unsigned short)f2bf(s[k] * inv);
    *(bf16x8*)(a.out[y] + (size_t)row * H + c * 8) = o;
  }
}

// ---------------- paired layer GEMM: m = rownorm(Agg@Wl + X@Wr + b); out=relu(bn(m+resid))
// v2: all A-fragments prefetched (keeps ~100 VGPRs live -> loads stay batched);
// resid staged coalesced into per-wave LDS; outputs transposed through LDS -> ushort8 stores.
// out aliases Aagg: block reads only its own 64-row range; reads precede stores (barriers).
struct MMArgs {
  const unsigned short* Aagg[2];
  const unsigned short* Xsrc[2];
  const unsigned short* resid[2];
  const unsigned short* wl[2];
  const unsigned short* wr[2];
  const float* bias[2];
  const float* bng[2]; const float* bnb[2]; const float* bnm[2]; const float* bnv[2];
  unsigned short* out[2];
};

__global__ __launch_bounds__(256, 4)
void layer_mm(MMArgs a, int n) {
  const int y = blockIdx.y;
  const int tid = threadIdx.x;
  const int lane = tid & 63;
  const int wv = tid >> 6;
  const int c = lane & 15;
  const int q = lane >> 4;
  const int row0 = blockIdx.x * 64;
  const int wrow0 = row0 + wv * 16;
  __shared__ unsigned short T[4][16 * 136];
  unsigned short* Tw = T[wv];

  int arow = wrow0 + c; if (arow >= n) arow = n - 1;

  // prefetch ALL A fragments (both operand matrices): 8 x 16B loads in flight
  bf16x8 af[8];
  {
    const unsigned short* a1 = a.Aagg[y] + (size_t)arow * H + q * 8;
    const unsigned short* a2 = a.Xsrc[y] + (size_t)arow * H + q * 8;
    #pragma unroll
    for (int ks = 0; ks < 4; ++ks) {
      af[ks]     = *(const bf16x8*)(a1 + ks * 32);
      af[4 + ks] = *(const bf16x8*)(a2 + ks * 32);
    }
  }
  // stage resid coalesced into per-wave LDS tile (16 rows x 128 cols)
  {
    const unsigned short* resid = a.resid[y];
    #pragma unroll
    for (int i = 0; i < 4; ++i) {
      int t2 = i * 64 + lane;          // ushort8-chunk id 0..255
      int r = t2 >> 4;                 // local row 0..15
      int cc = (t2 & 15) * 8;
      int rg = wrow0 + r; if (rg >= n) rg = n - 1;
      *(bf16x8*)&Tw[r * 136 + cc] = *(const bf16x8*)(resid + (size_t)rg * H + cc);
    }
  }
  __syncthreads();

  f32x4 acc[8];
  #pragma unroll
  for (int t = 0; t < 8; ++t) acc[t] = (f32x4){0.f, 0.f, 0.f, 0.f};
  {
    const unsigned short* wl = a.wl[y] + c * H + q * 8;
    const unsigned short* wr = a.wr[y] + c * H + q * 8;
    #pragma unroll
    for (int t = 0; t < 8; ++t) {
      #pragma unroll
      for (int ks = 0; ks < 4; ++ks) {
        bf16x8 bv = *(const bf16x8*)(wl + t * 16 * H + ks * 32);
        acc[t] = __builtin_amdgcn_mfma_f32_16x16x32_bf16(af[ks], bv, acc[t], 0, 0, 0);
      }
      #pragma unroll
      for (int ks = 0; ks < 4; ++ks) {
        bf16x8 bv = *(const bf16x8*)(wr + t * 16 * H + ks * 32);
        acc[t] = __builtin_amdgcn_mfma_f32_16x16x32_bf16(af[4 + ks], bv, acc[t], 0, 0, 0);
      }
    }
  }

  // epilogue: bias, rownorm, +resid(LDS), BN, relu -> write back into LDS tile
  float bia[8], sg[8], ofs[8];
  {
    const float* bias = a.bias[y];
    const float* bng = a.bng[y]; const float* bnb = a.bnb[y];
    const float* bnm = a.bnm[y]; const float* bnv = a.bnv[y];
    #pragma unroll
    for (int t = 0; t < 8; ++t) {
      int cc = t * 16 + c;
      bia[t] = bias[cc];
      float s = rsqrtf(bnv[cc] + 1e-5f) * bng[cc];
      sg[t] = s;
      ofs[t] = bnb[cc] - bnm[cc] * s;
    }
  }
  float ss[4] = {0.f, 0.f, 0.f, 0.f};
  #pragma unroll
  for (int t = 0; t < 8; ++t)
    #pragma unroll
    for (int r = 0; r < 4; ++r) {
      float v = acc[t][r] + bia[t];
      ss[r] = fmaf(v, v, ss[r]);
    }
  #pragma unroll
  for (int r = 0; r < 4; ++r) {
    ss[r] += __shfl_xor(ss[r], 1);
    ss[r] += __shfl_xor(ss[r], 2);
    ss[r] += __shfl_xor(ss[r], 4);
    ss[r] += __shfl_xor(ss[r], 8);
    ss[r] = 1.0f / fmaxf(sqrtf(ss[r]), 1e-12f);
  }
  #pragma unroll
  for (int r = 0; r < 4; ++r) {
    int lrw = q * 4 + r;
    #pragma unroll
    for (int t = 0; t < 8; ++t) {
      float rr = bf2f(Tw[lrw * 136 + t * 16 + c]);
      float v = fmaf(acc[t][r] + bia[t], ss[r], rr);
      v = fmaxf(fmaf(v, sg[t], ofs[t]), 0.f);
      Tw[lrw * 136 + t * 16 + c] = (unsigned short)f2bf(v);
    }
  }
  __syncthreads();
  // coalesced store-out
  {
    unsigned short* out = a.out[y];
    #pragma unroll
    for (int i = 0; i < 4; ++i) {
      int t2 = i * 64 + lane;
      int r = t2 >> 4;
      int cc = (t2 & 15) * 8;
      int rg = wrow0 + r;
      if (rg < n) *(bf16x8*)(out + (size_t)rg * H + cc) = *(const bf16x8*)&Tw[r * 136 + cc];
    }
  }
}

// ---------------- fused classifier: out = relu(h@W1+b1)@W2 + b2 (h is bf16) ----------
__global__ __launch_bounds__(256)
void classifier(const unsigned short* __restrict__ h, const float* __restrict__ W1,
                const float* __restrict__ b1, const float* __restrict__ W2,
                const float* __restrict__ b2, float* __restrict__ out, int n) {
  __shared__ float W1s[128 * 64];
  __shared__ float W2s[64 * 32];
  __shared__ float Hs[64 * 68];
  const int tid = threadIdx.x;
  const int row0 = blockIdx.x * 64;
  {
    const float4* s = (const float4*)W1;
    float4* d = (float4*)W1s;
    #pragma unroll
    for (int i = 0; i < 8; ++i) d[i * 256 + tid] = s[i * 256 + tid];
    const float4* s2 = (const float4*)W2;
    float4* d2 = (float4*)W2s;
    #pragma unroll
    for (int i = 0; i < 2; ++i) d2[i * 256 + tid] = s2[i * 256 + tid];
  }
  const int tm = tid >> 4;
  const int tn = tid & 15;
  float acc1[4][4];
  #pragma unroll
  for (int j = 0; j < 4; ++j)
    #pragma unroll
    for (int i = 0; i < 4; ++i) acc1[j][i] = 0.f;

  for (int kh = 0; kh < 2; ++kh) {
    const int k0 = kh << 6;
    const int lr = tid >> 4, lk = (tid & 15) << 2;
    #pragma unroll
    for (int j = 0; j < 4; ++j) {
      int r = lr + (j << 4);
      int rg = row0 + r; rg = rg < n ? rg : n - 1;
      ushort4 v = *(const ushort4*)(h + (size_t)rg * H + k0 + lk);
      float f[4] = {bf2f(v.x), bf2f(v.y), bf2f(v.z), bf2f(v.w)};
      st4(&Hs[r * 68 + lk], f);
    }
    __syncthreads();
    #pragma unroll 8
    for (int kk = 0; kk < 64; ++kk) {
      float4 w = *(const float4*)(&W1s[(k0 + kk) * 64 + (tn << 2)]);
      #pragma unroll
      for (int j = 0; j < 4; ++j) {
        float aa = Hs[(tm + (j << 4)) * 68 + kk];
        acc1[j][0] = fmaf(aa, w.x, acc1[j][0]);
        acc1[j][1] = fmaf(aa, w.y, acc1[j][1]);
        acc1[j][2] = fmaf(aa, w.z, acc1[j][2]);
        acc1[j][3] = fmaf(aa, w.w, acc1[j][3]);
      }
    }
    __syncthreads();
  }
  {
    float bb[4]; ld4(bb, b1 + (tn << 2));
    #pragma unroll
    for (int j = 0; j < 4; ++j) {
      int r = tm + (j << 4);
      float hv[4];
      #pragma unroll
      for (int i = 0; i < 4; ++i) hv[i] = fmaxf(acc1[j][i] + bb[i], 0.f);
      st4(&Hs[r * 68 + (tn << 2)], hv);
    }
  }
  __syncthreads();
  const int r2 = tid >> 2;
  const int cg = tid & 3;
  float acc2[8];
  #pragma unroll
  for (int i = 0; i < 8; ++i) acc2[i] = 0.f;
  #pragma unroll 8
  for (int k = 0; k < 64; ++k) {
    float hh = Hs[r2 * 68 + k];
    float4 w0 = *(const float4*)(&W2s[k * 32 + (cg << 3)]);
    float4 w1 = *(const float4*)(&W2s[k * 32 + (cg << 3) + 4]);
    acc2[0] = fmaf(hh, w0.x, acc2[0]);
    acc2[1] = fmaf(hh, w0.y, acc2[1]);
    acc2[2] = fmaf(hh, w0.z, acc2[2]);
    acc2[3] = fmaf(hh, w0.w, acc2[3]);
    acc2[4] = fmaf(hh, w1.x, acc2[4]);
    acc2[5] = fmaf(hh, w1.y, acc2[5]);
    acc2[6] = fmaf(hh, w1.z, acc2[6]);
    acc2[7] = fmaf(hh, w1.w, acc2[7]);
  }
  int rg = row0 + r2;
  if (rg < n) {
    float bb[8]; ld4(bb, b2 + (cg << 3)); ld4(bb + 4, b2 + (cg << 3) + 4);
    float o[8];
    #pragma unroll
    for (int i = 0; i < 8; ++i) o[i] = acc2[i] + bb[i];
    st4(out + (size_t)rg * 32 + (cg << 3), o);
    st4(out + (size_t)rg * 32 + (cg << 3) + 4, o + 4);
  }
}

extern "C" void kernel_launch(void* const* d_in, const int* in_sizes, int n_in,
                              void* d_out, int out_size, void* d_ws, size_t ws_size,
                              hipStream_t stream) {
  const float* x_user     = (const float*)d_in[0];
  const float* x_item     = (const float*)d_in[1];
  const float* enc_W_user = (const float*)d_in[2];
  const float* enc_b_user = (const float*)d_in[3];
  const float* enc_W_item = (const float*)d_in[4];
  const float* enc_b_item = (const float*)d_in[5];
  const float* Wl_ui = (const float*)d_in[6];
  const float* bl_ui = (const float*)d_in[7];
  const float* Wr_ui = (const float*)d_in[8];
  const float* Wl_iu = (const float*)d_in[9];
  const float* bl_iu = (const float*)d_in[10];
  const float* Wr_iu = (const float*)d_in[11];
  const float* bn_g_user = (const float*)d_in[12];
  const float* bn_b_user = (const float*)d_in[13];
  const float* bn_m_user = (const float*)d_in[14];
  const float* bn_v_user = (const float*)d_in[15];
  const float* bn_g_item = (const float*)d_in[16];
  const float* bn_b_item = (const float*)d_in[17];
  const float* bn_m_item = (const float*)d_in[18];
  const float* bn_v_item = (const float*)d_in[19];
  const float* cls_W1 = (const float*)d_in[20];
  const float* cls_b1 = (const float*)d_in[21];
  const float* cls_W2 = (const float*)d_in[22];
  const float* cls_b2 = (const float*)d_in[23];
  const int* ei_ui = (const int*)d_in[24];
  const int* ei_iu = (const int*)d_in[25];

  const int N_ = in_sizes[0] / H;       // 100000
  const int E_ = in_sizes[24] / 2;      // 1600000
  const size_t NH = (size_t)N_ * H;
  const int NBK = (N_ + BW - 1) >> BSH;        // 782
  const int CAP = E_ / NBK + 512;              // ~2558

  unsigned short* bufA = (unsigned short*)d_ws;
  unsigned short* bufB = bufA + NH;
  unsigned short* bufC = bufB + NH;
  unsigned short* bufD = bufC + NH;
  unsigned short* wt   = bufD + NH;     // 14 x 128 x 128
  int* ip = (int*)(wt + 14 * 16384);
  int* rp_ui  = ip; ip += N_ + 1;
  int* rp_iu  = ip; ip += N_ + 1;
  int* col_ui = ip; ip += E_;
  int* col_iu = ip; ip += E_;
  int* gcnt   = ip; ip += 2 * NBK;
  int* gbase  = ip; ip += 2 * (NBK + 1);
  unsigned int* buck = (unsigned int*)ip;      // 2 * NBK * CAP

  WPtrs wp;
  wp.s[0] = enc_W_user; wp.s[1] = enc_W_item;
  for (int l = 0; l < 3; ++l) {
    wp.s[2 + l]  = Wl_ui + (size_t)l * H * H;
    wp.s[5 + l]  = Wr_ui + (size_t)l * H * H;
    wp.s[8 + l]  = Wl_iu + (size_t)l * H * H;
    wp.s[11 + l] = Wr_iu + (size_t)l * H * H;
  }
  for (int m = 0; m < 14; ++m) wp.d[m] = wt + (size_t)m * 16384;

  const int GB = (N_ + 63) / 64;
  const int AB = (N_ + 3) / 4;

  zero_small<<<1, 256, 0, stream>>>(gcnt, 2 * NBK);
  conv_w<<<dim3(64, 14), 256, 0, stream>>>(wp);
  bucketize<<<dim3((E_ + 4095) / 4096, 2), 256, 0, stream>>>(ei_ui, ei_iu, E_, buck, gcnt, NBK, CAP);
  bucket_scan<<<1, 256, 0, stream>>>(gcnt, gbase, rp_ui, rp_iu, NBK, E_, N_);
  csr_build<<<dim3(NBK, 2), 256, 0, stream>>>(buck, gcnt, gbase, rp_ui, rp_iu, col_ui, col_iu, NBK, CAP, N_);

  EncArgs ea;
  ea.x[0] = x_user; ea.x[1] = x_item;
  ea.wt[0] = wt; ea.wt[1] = wt + 16384;
  ea.b[0] = enc_b_user; ea.b[1] = enc_b_item;
  ea.out[0] = bufA; ea.out[1] = bufB;
  enc_gemm<<<dim3(GB, 2), 256, 0, stream>>>(ea, N_);

  unsigned short* hu_c = bufA; unsigned short* hi_c = bufB;
  unsigned short* sp0 = bufC;  unsigned short* sp1 = bufD;
  for (int l = 0; l < 3; ++l) {
    const size_t bo = (size_t)l * H;
    AggArgs aa;
    aa.gt[0] = hi_c; aa.rp[0] = rp_iu; aa.col[0] = col_iu; aa.out[0] = sp0;
    aa.gt[1] = hu_c; aa.rp[1] = rp_ui; aa.col[1] = col_ui; aa.out[1] = sp1;
    agg_pair<<<dim3(AB, 2), 256, 0, stream>>>(aa, N_);
    MMArgs ma;
    ma.Aagg[0] = sp0; ma.Xsrc[0] = hi_c; ma.resid[0] = hu_c;
    ma.wl[0] = wt + (size_t)(8 + l) * 16384; ma.wr[0] = wt + (size_t)(11 + l) * 16384;
    ma.bias[0] = bl_iu + bo;
    ma.bng[0] = bn_g_user + bo; ma.bnb[0] = bn_b_user + bo;
    ma.bnm[0] = bn_m_user + bo; ma.bnv[0] = bn_v_user + bo;
    ma.out[0] = sp0;
    ma.Aagg[1] = sp1; ma.Xsrc[1] = hu_c; ma.resid[1] = hi_c;
    ma.wl[1] = wt + (size_t)(2 + l) * 16384; ma.wr[1] = wt + (size_t)(5 + l) * 16384;
    ma.bias[1] = bl_ui + bo;
    ma.bng[1] = bn_g_item + bo; ma.bnb[1] = bn_b_item + bo;
    ma.bnm[1] = bn_m_item + bo; ma.bnv[1] = bn_v_item + bo;
    ma.out[1] = sp1;
    layer_mm<<<dim3(GB, 2), 256, 0, stream>>>(ma, N_);
    unsigned short* t0 = hu_c; unsigned short* t1 = hi_c;
    hu_c = sp0; hi_c = sp1;
    sp0 = t0; sp1 = t1;
  }

  classifier<<<GB, 256, 0, stream>>>(hu_c, cls_W1, cls_b1, cls_W2, cls_b2,
                                     (float*)d_out, N_);
}

// Round 7
// 808.706 us; speedup vs baseline: 2.3933x; 1.2981x over previous
//
#include <hip/hip_runtime.h>
#include <cstdint>

#define H 128
#define BW 128          // bucket node width
#define BSH 7

typedef __attribute__((ext_vector_type(8))) short bf16x8;
typedef __attribute__((ext_vector_type(4))) float f32x4;

__device__ __forceinline__ float bf2f(unsigned short u) {
  union { unsigned int i; float f; } v; v.i = ((unsigned int)u) << 16; return v.f;
}
__device__ __forceinline__ unsigned int f2bf(float f) {
  unsigned int x = __float_as_uint(f);
  return (x + 0x7fffu + ((x >> 16) & 1u)) >> 16;   // RNE
}
__device__ __forceinline__ void ld4(float* d, const float* s) {
  float4 v = *(const float4*)s; d[0] = v.x; d[1] = v.y; d[2] = v.z; d[3] = v.w;
}
__device__ __forceinline__ void st4(float* d, const float* s) {
  float4 v; v.x = s[0]; v.y = s[1]; v.z = s[2]; v.w = s[3]; *(float4*)d = v;
}

// ---------------- weight transpose+convert: Wt[n][k] = bf16(W[k][n]) ----------------
struct WPtrs { const float* s[14]; unsigned short* d[14]; };

__global__ __launch_bounds__(256)
void conv_w(WPtrs p) {
  int m = blockIdx.y;
  int t = blockIdx.x * 256 + threadIdx.x;    // t = n*128 + k
  int nn = t >> 7, kk = t & 127;
  p.d[m][t] = (unsigned short)f2bf(p.s[m][kk * 128 + nn]);
}

__global__ __launch_bounds__(256)
void zero_small(int* __restrict__ p, int n) {
  for (int i = threadIdx.x; i < n; i += 256) p[i] = 0;
}

// ---------------- bucketize edges by dst>>BSH ----------------
// payload: (dst & 127) << 17 | src   (src < 2^17)
__global__ __launch_bounds__(256)
void bucketize(const int* __restrict__ e_ui, const int* __restrict__ e_iu, int E,
               unsigned int* __restrict__ buck, int* __restrict__ gcnt,
               int NBK, int CAP) {
  const int y = blockIdx.y;
  const int* src = y ? e_iu : e_ui;
  const int* dst = src + E;
  unsigned int* bk = buck + (size_t)y * NBK * CAP;
  int* gc = gcnt + y * NBK;
  __shared__ int bin[800];
  __shared__ int res[800];
  const int tid = threadIdx.x;
  for (int i = tid; i < NBK; i += 256) bin[i] = 0;
  __syncthreads();
  unsigned int pay[16]; int meta[16];
  const int base = blockIdx.x * 4096;
  #pragma unroll
  for (int r = 0; r < 16; ++r) {
    int i = base + r * 256 + tid;
    if (i < E) {
      int s = src[i], d = dst[i];
      int b = d >> BSH;
      int lo = atomicAdd(&bin[b], 1);
      pay[r] = ((unsigned int)(d & (BW - 1)) << 17) | (unsigned int)s;
      meta[r] = (b << 12) | lo;
    } else meta[r] = -1;
  }
  __syncthreads();
  for (int i = tid; i < NBK; i += 256) res[i] = atomicAdd(&gc[i], bin[i]);
  __syncthreads();
  #pragma unroll
  for (int r = 0; r < 16; ++r) {
    if (meta[r] >= 0) {
      int b = meta[r] >> 12, lo = meta[r] & 4095;
      int p = res[b] + lo; if (p >= CAP) p = CAP - 1;   // overflow-safe clamp
      bk[(size_t)b * CAP + p] = pay[r];
    }
  }
}

// ---------------- scan bucket counts -> bucket col bases ----------------
__global__ __launch_bounds__(256)
void bucket_scan(const int* __restrict__ gcnt, int* __restrict__ gbase,
                 int* __restrict__ rp_ui, int* __restrict__ rp_iu, int NBK, int E, int N) {
  __shared__ int ts[256];
  const int t = threadIdx.x;
  for (int y = 0; y < 2; ++y) {
    const int* gc = gcnt + y * NBK;
    int* gb = gbase + y * (NBK + 1);
    int v[4]; int s = 0;
    #pragma unroll
    for (int k = 0; k < 4; ++k) { int i = t * 4 + k; v[k] = (i < NBK) ? gc[i] : 0; s += v[k]; }
    ts[t] = s; __syncthreads();
    for (int off = 1; off < 256; off <<= 1) {
      int u = (t >= off) ? ts[t - off] : 0;
      __syncthreads();
      ts[t] += u;
      __syncthreads();
    }
    int excl = ts[t] - s;
    #pragma unroll
    for (int k = 0; k < 4; ++k) { int i = t * 4 + k; if (i < NBK) gb[i] = excl; excl += v[k]; }
    if (t == 255) gb[NBK] = E;
    __syncthreads();
  }
  if (t == 0) { rp_ui[N] = E; rp_iu[N] = E; }
}

// ---------------- per-bucket CSR build (LDS degree+scan+scatter) ----------------
__global__ __launch_bounds__(256)
void csr_build(const unsigned int* __restrict__ buck, const int* __restrict__ gcnt,
               const int* __restrict__ gbase, int* __restrict__ rp_ui, int* __restrict__ rp_iu,
               int* __restrict__ col_ui, int* __restrict__ col_iu, int NBK, int CAP, int N) {
  const int y = blockIdx.y, b = blockIdx.x, t = threadIdx.x;
  const unsigned int* bk = buck + ((size_t)y * NBK + b) * CAP;
  int cnt = gcnt[y * NBK + b];
  if (cnt > CAP) cnt = CAP;
  const int basec = gbase[y * (NBK + 1) + b];
  int* rp = y ? rp_iu : rp_ui;
  int* col = y ? col_iu : col_ui;
  __shared__ int deg[BW], cur[BW];
  if (t < BW) deg[t] = 0;
  __syncthreads();
  for (int j = t; j < cnt; j += 256) atomicAdd(&deg[bk[j] >> 17], 1);
  __syncthreads();
  if (t < BW) cur[t] = deg[t];
  __syncthreads();
  for (int off = 1; off < BW; off <<= 1) {
    int u = (t < BW && t >= off) ? cur[t - off] : 0;
    __syncthreads();
    if (t < BW) cur[t] += u;
    __syncthreads();
  }
  const int lo = b << BSH;
  if (t < BW) {
    int excl = cur[t] - deg[t];
    int node = lo + t;
    if (node < N) rp[node] = basec + excl;
    cur[t] = excl;
  }
  __syncthreads();
  for (int j = t; j < cnt; j += 256) {
    unsigned int u = bk[j];
    int pos = basec + atomicAdd(&cur[u >> 17], 1);
    col[pos] = (int)(u & 0x1FFFFu);
  }
}

// ---------------- encoder GEMM: out = bf16(relu(x @ W + b)) ----------------
struct EncArgs {
  const float* x[2];
  const unsigned short* wt[2];
  const float* b[2];
  unsigned short* out[2];
};

__global__ __launch_bounds__(256)
void enc_gemm(EncArgs a, int n) {
  const int y = blockIdx.y;
  const int tid = threadIdx.x;
  const int lane = tid & 63, wv = tid >> 6;
  const int c = lane & 15, q = lane >> 4;
  const int row0 = blockIdx.x * 64;
  __shared__ unsigned short As[64 * 136];
  const float* x = a.x[y];
  #pragma unroll
  for (int k = 0; k < 8; ++k) {
    int idx = k * 256 + tid;           // float4 id
    int r = idx >> 5;                  // 32 float4 per row
    int cc = (idx & 31) * 4;
    int rg = row0 + r; if (rg >= n) rg = n - 1;
    float4 v = *(const float4*)(x + (size_t)rg * H + cc);
    ushort4 o;
    o.x = (unsigned short)f2bf(v.x); o.y = (unsigned short)f2bf(v.y);
    o.z = (unsigned short)f2bf(v.z); o.w = (unsigned short)f2bf(v.w);
    *(ushort4*)&As[r * 136 + cc] = o;
  }
  __syncthreads();
  f32x4 acc[8];
  #pragma unroll
  for (int t = 0; t < 8; ++t) acc[t] = (f32x4){0.f, 0.f, 0.f, 0.f};
  const int lr = wv * 16 + c;
  const unsigned short* wb = a.wt[y] + c * H + q * 8;
  #pragma unroll
  for (int ks = 0; ks < 4; ++ks) {
    bf16x8 av = *(const bf16x8*)&As[lr * 136 + q * 8 + ks * 32];
    #pragma unroll
    for (int t = 0; t < 8; ++t) {
      bf16x8 bv = *(const bf16x8*)(wb + t * 16 * H + ks * 32);
      acc[t] = __builtin_amdgcn_mfma_f32_16x16x32_bf16(av, bv, acc[t], 0, 0, 0);
    }
  }
  const int wrow0 = row0 + wv * 16;
  unsigned short* out = a.out[y];
  const float* bias = a.b[y];
  float bia[8];
  #pragma unroll
  for (int t = 0; t < 8; ++t) bia[t] = bias[t * 16 + c];
  #pragma unroll
  for (int r = 0; r < 4; ++r) {
    int row = wrow0 + q * 4 + r;
    if (row < n) {
      #pragma unroll
      for (int t = 0; t < 8; ++t) {
        float v = fmaxf(acc[t][r] + bia[t], 0.f);
        out[(size_t)row * H + t * 16 + c] = (unsigned short)f2bf(v);
      }
    }
  }
}

// ---------------- paired CSR mean aggregation ----------------
// quarter-wave per edge: 16 lanes x 16B cover a 256B row; 4 edges per load instr.
struct AggArgs {
  const unsigned short* gt[2];
  const int* rp[2];
  const int* col[2];
  unsigned short* out[2];
};

__global__ __launch_bounds__(256)
void agg_pair(AggArgs a, int n) {
  const int y = blockIdx.y;
  const unsigned short* __restrict__ h = a.gt[y];
  const int* __restrict__ rp = a.rp[y];
  const int* __restrict__ col = a.col[y];
  int row = blockIdx.x * 4 + (threadIdx.x >> 6);
  if (row >= n) return;
  const int lane = threadIdx.x & 63;
  const int g = lane >> 4;          // edge group 0..3
  const int c = lane & 15;          // column chunk: cols c*8 .. c*8+7
  const int beg = rp[row], end = rp[row + 1];
  float s[8] = {0.f, 0.f, 0.f, 0.f, 0.f, 0.f, 0.f, 0.f};
  for (int j = beg; j < end; j += 16) {
    bf16x8 v[4]; float m[4];
    #pragma unroll
    for (int u = 0; u < 4; ++u) {
      int idx = j + u * 4 + g;
      int ii = idx < end ? idx : beg;          // always-valid col index
      m[u] = idx < end ? 1.f : 0.f;
      v[u] = *(const bf16x8*)(h + (size_t)col[ii] * H + c * 8);
    }
    #pragma unroll
    for (int u = 0; u < 4; ++u)
      #pragma unroll
      for (int k = 0; k < 8; ++k)
        s[k] = fmaf(m[u], bf2f((unsigned short)v[u][k]), s[k]);
  }
  #pragma unroll
  for (int k = 0; k < 8; ++k) {
    s[k] += __shfl_xor(s[k], 16);
    s[k] += __shfl_xor(s[k], 32);
  }
  int cdeg = end - beg;
  float inv = 1.0f / (float)(cdeg > 1 ? cdeg : 1);
  if (g == 0) {
    bf16x8 o;
    #pragma unroll
    for (int k = 0; k < 8; ++k) o[k] = (short)(unsigned short)f2bf(s[k] * inv);
    *(bf16x8*)(a.out[y] + (size_t)row * H + c * 8) = o;
  }
}

// ---------------- paired layer GEMM v3 ----------------
// m = rownorm(Agg@Wl + X@Wr + b); out = relu(bn(m + resid))
// B-fragments served from LDS: weights staged per block in frag-major layout
// (each (t,ks) fragment = contiguous 1KB; K-loop ds_read_b128 at base+lane*16 is
// stride-1 conflict-free). Two 32KB phases (Wl, Wr) through one buffer.
// out aliases Aagg: block reads only its own 64-row range; reads precede stores.
struct MMArgs {
  const unsigned short* Aagg[2];
  const unsigned short* Xsrc[2];
  const unsigned short* resid[2];
  const unsigned short* wl[2];
  const unsigned short* wr[2];
  const float* bias[2];
  const float* bng[2]; const float* bnb[2]; const float* bnm[2]; const float* bnv[2];
  unsigned short* out[2];
};

__global__ __launch_bounds__(256)
void layer_mm(MMArgs a, int n) {
  const int y = blockIdx.y;
  const int tid = threadIdx.x;
  const int lane = tid & 63;
  const int wv = tid >> 6;
  const int c = lane & 15;
  const int q = lane >> 4;
  const int row0 = blockIdx.x * 64;
  const int wrow0 = row0 + wv * 16;
  __shared__ unsigned short Wb[16384];       // 32 KB frag-major weight buffer
  __shared__ unsigned short T[4][16 * 136];  // 17.4 KB per-wave resid/out tiles
  unsigned short* Tw = T[wv];

  int arow = wrow0 + c; if (arow >= n) arow = n - 1;

  // A fragments (8 x 16B global loads)
  bf16x8 af[8];
  {
    const unsigned short* a1 = a.Aagg[y] + (size_t)arow * H + q * 8;
    const unsigned short* a2 = a.Xsrc[y] + (size_t)arow * H + q * 8;
    #pragma unroll
    for (int ks = 0; ks < 4; ++ks) {
      af[ks]     = *(const bf16x8*)(a1 + ks * 32);
      af[4 + ks] = *(const bf16x8*)(a2 + ks * 32);
    }
  }
  // stage resid coalesced into per-wave LDS tile (wave-private; no barrier needed)
  {
    const unsigned short* resid = a.resid[y];
    #pragma unroll
    for (int i = 0; i < 4; ++i) {
      int t2 = i * 64 + lane;
      int r = t2 >> 4;
      int cc = (t2 & 15) * 8;
      int rg = wrow0 + r; if (rg >= n) rg = n - 1;
      *(bf16x8*)&Tw[r * 136 + cc] = *(const bf16x8*)(resid + (size_t)rg * H + cc);
    }
  }

  f32x4 acc[8];
  #pragma unroll
  for (int t = 0; t < 8; ++t) acc[t] = (f32x4){0.f, 0.f, 0.f, 0.f};

  #pragma unroll
  for (int p = 0; p < 2; ++p) {
    const unsigned short* W = p ? a.wr[y] : a.wl[y];
    __syncthreads();   // p=0: entry sync; p=1: all Wb reads of phase 0 done
    // stage 32KB: chunk id -> (frag block b = id>>6: t=b>>2, ks=b&3; lane l=id&63: qq=l>>4, cc2=l&15)
    // src = W[(t*16+cc2)*H + ks*32 + qq*8] (16 rows x 64B contiguous per wave-instr)
    // dst = Wb[id*8] (perfectly contiguous)
    #pragma unroll
    for (int i = 0; i < 8; ++i) {
      int id = i * 256 + tid;
      int b = id >> 6, l = id & 63;
      int t = b >> 2, ks = b & 3, qq = l >> 4, cc2 = l & 15;
      bf16x8 v = *(const bf16x8*)(W + (t * 16 + cc2) * H + ks * 32 + qq * 8);
      *(bf16x8*)&Wb[id * 8] = v;
    }
    __syncthreads();
    #pragma unroll
    for (int t = 0; t < 8; ++t) {
      #pragma unroll
      for (int ks = 0; ks < 4; ++ks) {
        bf16x8 bv = *(const bf16x8*)&Wb[(((t << 2) + ks) * 64 + lane) * 8];
        acc[t] = __builtin_amdgcn_mfma_f32_16x16x32_bf16(af[(p << 2) + ks], bv, acc[t], 0, 0, 0);
      }
    }
  }

  // epilogue: bias, rownorm, +resid(LDS), BN, relu -> LDS tile -> coalesced store
  float bia[8], sg[8], ofs[8];
  {
    const float* bias = a.bias[y];
    const float* bng = a.bng[y]; const float* bnb = a.bnb[y];
    const float* bnm = a.bnm[y]; const float* bnv = a.bnv[y];
    #pragma unroll
    for (int t = 0; t < 8; ++t) {
      int cc = t * 16 + c;
      bia[t] = bias[cc];
      float s = rsqrtf(bnv[cc] + 1e-5f) * bng[cc];
      sg[t] = s;
      ofs[t] = bnb[cc] - bnm[cc] * s;
    }
  }
  float ss[4] = {0.f, 0.f, 0.f, 0.f};
  #pragma unroll
  for (int t = 0; t < 8; ++t)
    #pragma unroll
    for (int r = 0; r < 4; ++r) {
      float v = acc[t][r] + bia[t];
      ss[r] = fmaf(v, v, ss[r]);
    }
  #pragma unroll
  for (int r = 0; r < 4; ++r) {
    ss[r] += __shfl_xor(ss[r], 1);
    ss[r] += __shfl_xor(ss[r], 2);
    ss[r] += __shfl_xor(ss[r], 4);
    ss[r] += __shfl_xor(ss[r], 8);
    ss[r] = 1.0f / fmaxf(sqrtf(ss[r]), 1e-12f);
  }
  #pragma unroll
  for (int r = 0; r < 4; ++r) {
    int lrw = q * 4 + r;
    #pragma unroll
    for (int t = 0; t < 8; ++t) {
      float rr = bf2f(Tw[lrw * 136 + t * 16 + c]);
      float v = fmaf(acc[t][r] + bia[t], ss[r], rr);
      v = fmaxf(fmaf(v, sg[t], ofs[t]), 0.f);
      Tw[lrw * 136 + t * 16 + c] = (unsigned short)f2bf(v);
    }
  }
  // wave-private tile: in-wave LDS ordering suffices; store out coalesced
  {
    unsigned short* out = a.out[y];
    #pragma unroll
    for (int i = 0; i < 4; ++i) {
      int t2 = i * 64 + lane;
      int r = t2 >> 4;
      int cc = (t2 & 15) * 8;
      int rg = wrow0 + r;
      if (rg < n) *(bf16x8*)(out + (size_t)rg * H + cc) = *(const bf16x8*)&Tw[r * 136 + cc];
    }
  }
}

// ---------------- fused classifier: out = relu(h@W1+b1)@W2 + b2 (h is bf16) ----------
__global__ __launch_bounds__(256)
void classifier(const unsigned short* __restrict__ h, const float* __restrict__ W1,
                const float* __restrict__ b1, const float* __restrict__ W2,
                const float* __restrict__ b2, float* __restrict__ out, int n) {
  __shared__ float W1s[128 * 64];
  __shared__ float W2s[64 * 32];
  __shared__ float Hs[64 * 68];
  const int tid = threadIdx.x;
  const int row0 = blockIdx.x * 64;
  {
    const float4* s = (const float4*)W1;
    float4* d = (float4*)W1s;
    #pragma unroll
    for (int i = 0; i < 8; ++i) d[i * 256 + tid] = s[i * 256 + tid];
    const float4* s2 = (const float4*)W2;
    float4* d2 = (float4*)W2s;
    #pragma unroll
    for (int i = 0; i < 2; ++i) d2[i * 256 + tid] = s2[i * 256 + tid];
  }
  const int tm = tid >> 4;
  const int tn = tid & 15;
  float acc1[4][4];
  #pragma unroll
  for (int j = 0; j < 4; ++j)
    #pragma unroll
    for (int i = 0; i < 4; ++i) acc1[j][i] = 0.f;

  for (int kh = 0; kh < 2; ++kh) {
    const int k0 = kh << 6;
    const int lr = tid >> 4, lk = (tid & 15) << 2;
    #pragma unroll
    for (int j = 0; j < 4; ++j) {
      int r = lr + (j << 4);
      int rg = row0 + r; rg = rg < n ? rg : n - 1;
      ushort4 v = *(const ushort4*)(h + (size_t)rg * H + k0 + lk);
      float f[4] = {bf2f(v.x), bf2f(v.y), bf2f(v.z), bf2f(v.w)};
      st4(&Hs[r * 68 + lk], f);
    }
    __syncthreads();
    #pragma unroll 8
    for (int kk = 0; kk < 64; ++kk) {
      float4 w = *(const float4*)(&W1s[(k0 + kk) * 64 + (tn << 2)]);
      #pragma unroll
      for (int j = 0; j < 4; ++j) {
        float aa = Hs[(tm + (j << 4)) * 68 + kk];
        acc1[j][0] = fmaf(aa, w.x, acc1[j][0]);
        acc1[j][1] = fmaf(aa, w.y, acc1[j][1]);
        acc1[j][2] = fmaf(aa, w.z, acc1[j][2]);
        acc1[j][3] = fmaf(aa, w.w, acc1[j][3]);
      }
    }
    __syncthreads();
  }
  {
    float bb[4]; ld4(bb, b1 + (tn << 2));
    #pragma unroll
    for (int j = 0; j < 4; ++j) {
      int r = tm + (j << 4);
      float hv[4];
      #pragma unroll
      for (int i = 0; i < 4; ++i) hv[i] = fmaxf(acc1[j][i] + bb[i], 0.f);
      st4(&Hs[r * 68 + (tn << 2)], hv);
    }
  }
  __syncthreads();
  const int r2 = tid >> 2;
  const int cg = tid & 3;
  float acc2[8];
  #pragma unroll
  for (int i = 0; i < 8; ++i) acc2[i] = 0.f;
  #pragma unroll 8
  for (int k = 0; k < 64; ++k) {
    float hh = Hs[r2 * 68 + k];
    float4 w0 = *(const float4*)(&W2s[k * 32 + (cg << 3)]);
    float4 w1 = *(const float4*)(&W2s[k * 32 + (cg << 3) + 4]);
    acc2[0] = fmaf(hh, w0.x, acc2[0]);
    acc2[1] = fmaf(hh, w0.y, acc2[1]);
    acc2[2] = fmaf(hh, w0.z, acc2[2]);
    acc2[3] = fmaf(hh, w0.w, acc2[3]);
    acc2[4] = fmaf(hh, w1.x, acc2[4]);
    acc2[5] = fmaf(hh, w1.y, acc2[5]);
    acc2[6] = fmaf(hh, w1.z, acc2[6]);
    acc2[7] = fmaf(hh, w1.w, acc2[7]);
  }
  int rg = row0 + r2;
  if (rg < n) {
    float bb[8]; ld4(bb, b2 + (cg << 3)); ld4(bb + 4, b2 + (cg << 3) + 4);
    float o[8];
    #pragma unroll
    for (int i = 0; i < 8; ++i) o[i] = acc2[i] + bb[i];
    st4(out + (size_t)rg * 32 + (cg << 3), o);
    st4(out + (size_t)rg * 32 + (cg << 3) + 4, o + 4);
  }
}

extern "C" void kernel_launch(void* const* d_in, const int* in_sizes, int n_in,
                              void* d_out, int out_size, void* d_ws, size_t ws_size,
                              hipStream_t stream) {
  const float* x_user     = (const float*)d_in[0];
  const float* x_item     = (const float*)d_in[1];
  const float* enc_W_user = (const float*)d_in[2];
  const float* enc_b_user = (const float*)d_in[3];
  const float* enc_W_item = (const float*)d_in[4];
  const float* enc_b_item = (const float*)d_in[5];
  const float* Wl_ui = (const float*)d_in[6];
  const float* bl_ui = (const float*)d_in[7];
  const float* Wr_ui = (const float*)d_in[8];
  const float* Wl_iu = (const float*)d_in[9];
  const float* bl_iu = (const float*)d_in[10];
  const float* Wr_iu = (const float*)d_in[11];
  const float* bn_g_user = (const float*)d_in[12];
  const float* bn_b_user = (const float*)d_in[13];
  const float* bn_m_user = (const float*)d_in[14];
  const float* bn_v_user = (const float*)d_in[15];
  const float* bn_g_item = (const float*)d_in[16];
  const float* bn_b_item = (const float*)d_in[17];
  const float* bn_m_item = (const float*)d_in[18];
  const float* bn_v_item = (const float*)d_in[19];
  const float* cls_W1 = (const float*)d_in[20];
  const float* cls_b1 = (const float*)d_in[21];
  const float* cls_W2 = (const float*)d_in[22];
  const float* cls_b2 = (const float*)d_in[23];
  const int* ei_ui = (const int*)d_in[24];
  const int* ei_iu = (const int*)d_in[25];

  const int N_ = in_sizes[0] / H;       // 100000
  const int E_ = in_sizes[24] / 2;      // 1600000
  const size_t NH = (size_t)N_ * H;
  const int NBK = (N_ + BW - 1) >> BSH;        // 782
  const int CAP = E_ / NBK + 512;              // ~2558

  unsigned short* bufA = (unsigned short*)d_ws;
  unsigned short* bufB = bufA + NH;
  unsigned short* bufC = bufB + NH;
  unsigned short* bufD = bufC + NH;
  unsigned short* wt   = bufD + NH;     // 14 x 128 x 128
  int* ip = (int*)(wt + 14 * 16384);
  int* rp_ui  = ip; ip += N_ + 1;
  int* rp_iu  = ip; ip += N_ + 1;
  int* col_ui = ip; ip += E_;
  int* col_iu = ip; ip += E_;
  int* gcnt   = ip; ip += 2 * NBK;
  int* gbase  = ip; ip += 2 * (NBK + 1);
  unsigned int* buck = (unsigned int*)ip;      // 2 * NBK * CAP

  WPtrs wp;
  wp.s[0] = enc_W_user; wp.s[1] = enc_W_item;
  for (int l = 0; l < 3; ++l) {
    wp.s[2 + l]  = Wl_ui + (size_t)l * H * H;
    wp.s[5 + l]  = Wr_ui + (size_t)l * H * H;
    wp.s[8 + l]  = Wl_iu + (size_t)l * H * H;
    wp.s[11 + l] = Wr_iu + (size_t)l * H * H;
  }
  for (int m = 0; m < 14; ++m) wp.d[m] = wt + (size_t)m * 16384;

  const int GB = (N_ + 63) / 64;
  const int AB = (N_ + 3) / 4;

  zero_small<<<1, 256, 0, stream>>>(gcnt, 2 * NBK);
  conv_w<<<dim3(64, 14), 256, 0, stream>>>(wp);
  bucketize<<<dim3((E_ + 4095) / 4096, 2), 256, 0, stream>>>(ei_ui, ei_iu, E_, buck, gcnt, NBK, CAP);
  bucket_scan<<<1, 256, 0, stream>>>(gcnt, gbase, rp_ui, rp_iu, NBK, E_, N_);
  csr_build<<<dim3(NBK, 2), 256, 0, stream>>>(buck, gcnt, gbase, rp_ui, rp_iu, col_ui, col_iu, NBK, CAP, N_);

  EncArgs ea;
  ea.x[0] = x_user; ea.x[1] = x_item;
  ea.wt[0] = wt; ea.wt[1] = wt + 16384;
  ea.b[0] = enc_b_user; ea.b[1] = enc_b_item;
  ea.out[0] = bufA; ea.out[1] = bufB;
  enc_gemm<<<dim3(GB, 2), 256, 0, stream>>>(ea, N_);

  unsigned short* hu_c = bufA; unsigned short* hi_c = bufB;
  unsigned short* sp0 = bufC;  unsigned short* sp1 = bufD;
  for (int l = 0; l < 3; ++l) {
    const size_t bo = (size_t)l * H;
    AggArgs aa;
    aa.gt[0] = hi_c; aa.rp[0] = rp_iu; aa.col[0] = col_iu; aa.out[0] = sp0;
    aa.gt[1] = hu_c; aa.rp[1] = rp_ui; aa.col[1] = col_ui; aa.out[1] = sp1;
    agg_pair<<<dim3(AB, 2), 256, 0, stream>>>(aa, N_);
    MMArgs ma;
    ma.Aagg[0] = sp0; ma.Xsrc[0] = hi_c; ma.resid[0] = hu_c;
    ma.wl[0] = wt + (size_t)(8 + l) * 16384; ma.wr[0] = wt + (size_t)(11 + l) * 16384;
    ma.bias[0] = bl_iu + bo;
    ma.bng[0] = bn_g_user + bo; ma.bnb[0] = bn_b_user + bo;
    ma.bnm[0] = bn_m_user + bo; ma.bnv[0] = bn_v_user + bo;
    ma.out[0] = sp0;
    ma.Aagg[1] = sp1; ma.Xsrc[1] = hu_c; ma.resid[1] = hi_c;
    ma.wl[1] = wt + (size_t)(2 + l) * 16384; ma.wr[1] = wt + (size_t)(5 + l) * 16384;
    ma.bias[1] = bl_ui + bo;
    ma.bng[1] = bn_g_item + bo; ma.bnb[1] = bn_b_item + bo;
    ma.bnm[1] = bn_m_item + bo; ma.bnv[1] = bn_v_item + bo;
    ma.out[1] = sp1;
    layer_mm<<<dim3(GB, 2), 256, 0, stream>>>(ma, N_);
    unsigned short* t0 = hu_c; unsigned short* t1 = hi_c;
    hu_c = sp0; hi_c = sp1;
    sp0 = t0; sp1 = t1;
  }

  classifier<<<GB, 256, 0, stream>>>(hu_c, cls_W1, cls_b1, cls_W2, cls_b2,
                                     (float*)d_out, N_);
}